// Round 1
// baseline (180.403 us; speedup 1.0000x reference)
//
#include <hip/hip_runtime.h>
#include <stdint.h>

#define BATCH 32
#define H 512
#define W 512
#define NACC 16
#define TH 32              // center rows per tile
#define HALO 9             // coverage steps a=1..9
#define RH (TH + 2*HALO)   // 50 rows incl. halo
#define NWORDS (RH*8)      // 400 mask words per image
#define NT 1024
#define NW (NT/64)         // 16 waves
#define NTILE (H/TH)       // 16
#define NBLK (NTILE*BATCH) // 512 blocks = 2/CU

// part[fid*NACC + k] per-block partials (no atomics, deterministic):
//  0: sum(p*g)  1: sum(p)  2: sum(g)
//  3: cnt_pe 4: cnt_pm 5: cnt_pj  6: cnt_ge 7: cnt_gm 8: cnt_gj
//  9: int_e 10: int_m 11: int_j
// 12: dsum_p2g 13: cnt_p2g 14: dsum_g2p 15: cnt_g2p

// LB(NT,8) forces 64-VGPR budget -> spill storm (R7/R8). LB(NT,4) is safe.
__global__ __launch_bounds__(NT, 4) void fused_kernel(
    const float* __restrict__ pred, const float* __restrict__ gt,
    float* __restrict__ part)
{
    __shared__ uint64_t MpS[NWORDS + 2];   // single-buffer + pad word each end
    __shared__ uint64_t MgS[NWORDS + 2];
    __shared__ float    EC[2][TH];         // pred colsums at cols 255|256
    __shared__ float    redf[NW][2];
    __shared__ unsigned redu[NW][5];

    uint64_t* Mp = MpS + 1;   // flat index o = row*8 + word
    uint64_t* Mg = MgS + 1;

    // fid = tile*32 + b: vertically-adjacent tiles of one image are 32 apart
    // => same XCD under mod-8 round-robin dispatch (halo rows share L2).
    int fid  = blockIdx.x;
    int b    = fid & 31;
    int tile = fid >> 5;

    const float* pimg = pred + (size_t)b * H * W;
    const float* gimg = gt   + (size_t)b * H * W;
    int y0 = tile * TH;
    int tid = threadIdx.x, lane = tid & 63, wid = tid >> 6;

    // ---- Phase 1: ballot masks + dice sums, rows y0-9..y0+40.
    // 400 = 5 outer x 5 unroll x 16 waves EXACTLY: no s-bounds guard needed,
    // 10 global loads in flight per wave iteration. Per-thread task order is
    // identical to the old x4 version (s = wid + 16*j ascending) -> dice
    // partials bitwise unchanged.
    float v0 = 0.f, v1 = 0.f;
    for (int k = 0; k < 5; ++k) {
        int s0 = wid + 80 * k;
        float vp[5], vg[5];
        #pragma unroll
        for (int u = 0; u < 5; ++u) {
            int s = s0 + u * NW;
            vp[u] = 0.f; vg[u] = 0.f;
            int ry = y0 - HALO + (s >> 3);
            if ((unsigned)ry < (unsigned)H) {
                int i0 = ry * W + (s & 7) * 64 + lane;
                vp[u] = pimg[i0]; vg[u] = gimg[i0];
            }
        }
        #pragma unroll
        for (int u = 0; u < 5; ++u) {
            int s = s0 + u * NW;
            unsigned long long mp = __ballot(vp[u] > 0.5f);
            unsigned long long mg = __ballot(vg[u] > 0.5f);
            if (lane == 0) { Mp[s] = mp; Mg[s] = mg; }
            int r = s >> 3;
            if (r >= HALO && r < HALO + TH) {
                v1 += vp[u];
                v0 += (vg[u] > 0.5f) ? vp[u] : 0.f;
            }
        }
    }
    if (tid == 0) { MpS[0] = 0; MpS[NWORDS + 1] = 0; MgS[0] = 0; MgS[NWORDS + 1] = 0; }

    // Stencil-wave pre-barrier prefetch (latency overlaps the barrier drain)
    bool isStencil = tid >= 512;
    int idx = tid & 511;
    int qi = idx & 127, h2 = idx >> 7;    // h2 in 0..3, 8 rows each
    int x4 = qi * 4;
    int ys = y0 + h2 * 8;
    float4 pm4 = make_float4(0, 0, 0, 0), pc4 = make_float4(0, 0, 0, 0);
    if (isStencil) {
        if (ys > 0) pm4 = *(const float4*)(pimg + (size_t)(ys - 1) * W + x4);
        pc4 = *(const float4*)(pimg + (size_t)ys * W + x4);
    }

    // pred edge colsums (cols 255,256) for the cross-wave stencil halo
    if (tid < 2 * TH) {
        int c = tid >> 5, r = tid & (TH - 1);
        int y = y0 + r, col = 255 + c;
        float sum = (y > 0     ? pimg[(size_t)(y - 1) * W + col] : 0.f)
                  +              pimg[(size_t)y * W + col]
                  + (y < H - 1 ? pimg[(size_t)(y + 1) * W + col] : 0.f);
        EC[c][r] = sum;
    }
    __syncthreads();
    // ======== NO MORE BARRIERS until the final reduce ========

    uint64_t cpack = 0ULL;      // stencil waves: 9 counters, 7-bit fields
    int dsum = 0, dcnt = 0;     // distance waves

    if (isStencil) {
        // ---- Stencil: pred via floats (rolling rows), gt via bit popcounts.
        // Software-pipelined: row r+1's global float4 and win6 window are
        // issued before row r's compute (breaks 8 exposed load->use chains).
        int wdx = qi >> 4;                    // gt word for this quad
        int ss = (qi & 15) * 4;               // bit offset of x4 in word
        auto win6 = [&](int rb) -> uint32_t {
            const uint64_t* row = &Mg[rb * 8];
            uint64_t bm = row[wdx];
            if (ss == 0) {
                uint64_t lo = wdx ? row[wdx - 1] : 0ULL;
                return (uint32_t)(((bm << 1) | (lo >> 63)) & 0x3FULL);
            }
            uint32_t v = (uint32_t)((bm >> (ss - 1)) & 0x3FULL);
            if (ss == 60) {
                uint64_t hi = (wdx < 7) ? row[wdx + 1] : 0ULL;
                v |= ((uint32_t)hi & 1u) << 5;
            }
            return v;
        };
        int rb0 = h2 * 8 + HALO - 1;          // bit-row of (ys-1)
        uint32_t wU = win6(rb0), wM = win6(rb0 + 1);
        uint32_t wDf = win6(rb0 + 2);         // prefetched window for r=0
        float4 ppf;                           // prefetched row ys+1 for r=0
        {
            int yp = ys + 1;
            ppf = (yp < H) ? *(const float4*)(pimg + (size_t)yp * W + x4)
                           : make_float4(0, 0, 0, 0);
        }

        for (int r = 0; r < 8; ++r) {
            float4 pp4 = ppf;
            uint32_t wD = wDf;
            if (r < 7) {                      // prefetch for row r+1
                int yp = ys + r + 2;
                ppf = (yp < H) ? *(const float4*)(pimg + (size_t)yp * W + x4)
                               : make_float4(0, 0, 0, 0);
                wDf = win6(rb0 + 3 + r);
            }
            int ry = h2 * 8 + r;

            float ps[6];
            ps[1] = pm4.x + pc4.x + pp4.x; ps[2] = pm4.y + pc4.y + pp4.y;
            ps[3] = pm4.z + pc4.z + pp4.z; ps[4] = pm4.w + pc4.w + pp4.w;
            float psl = __shfl_up(ps[4], 1, 64);
            float psr = __shfl_down(ps[1], 1, 64);
            if (lane == 0)  psl = (qi == 0)   ? 0.f : EC[0][ry];
            if (lane == 63) psr = (qi == 127) ? 0.f : EC[1][ry];
            ps[0] = psl; ps[5] = psr;

            float pcv[4] = {pc4.x, pc4.y, pc4.z, pc4.w};
            #pragma unroll
            for (int j = 0; j < 4; ++j) {
                float np = ps[j] + ps[j + 1] + ps[j + 2] - pcv[j];
                bool pon = pcv[j] > 0.5f;
                bool pe  = pon && (np == 1.f);
                bool pmb = pon && (np == 2.f);
                bool pjb = pon && (np > 2.f);
                uint32_t n9 = ((wU >> j) & 7u) | (((wM >> j) & 7u) << 3) | (((wD >> j) & 7u) << 6);
                uint32_t cen = (wM >> (j + 1)) & 1u;
                int ng = __popc(n9) - (int)cen;
                bool gon = cen != 0u;
                bool ge  = gon && (ng == 1);
                bool gmb = gon && (ng == 2);
                bool gjb = gon && (ng > 2);
                cpack += (uint64_t)pe
                       | ((uint64_t)pmb << 7)
                       | ((uint64_t)pjb << 14)
                       | ((uint64_t)ge  << 21)
                       | ((uint64_t)gmb << 28)
                       | ((uint64_t)gjb << 35)
                       | ((uint64_t)(pe  && ge)  << 42)
                       | ((uint64_t)(pmb && gmb) << 49)
                       | ((uint64_t)(pjb && gjb) << 56);
            }
            pm4 = pc4; pc4 = pp4; wU = wM; wM = wD;
        }
    } else {
        // ---- Distance: barrier-free register dilation (verified R10-R12).
        // C_a = S_a(V_a); incremental C_a = C_{a-1}|S_{a-1}(N_a)|shift_a(V_a)
        // Software-pipelined: iteration a+1's 6 ds_read_b64 are issued before
        // iteration a's cascade (LDS latency hides under ~35 VALU ops).
        bool isP = tid < 256;                  // waves 0-3: p2g; 4-7: g2p
        int di = tid & 255;
        int o  = (HALO + (di >> 3)) * 8 + (di & 7);  // rc in [9,40]
        int w  = di & 7;
        bool wL = (w > 0), wR = (w < 7);
        const uint64_t* MT = isP ? Mp : Mg;
        const uint64_t* MV = isP ? Mg : Mp;

        uint64_t T = MT[o];
        dcnt = __popcll(T);
        dsum = dcnt;                           // a=0 baseline (dist >= 1)
        uint64_t VM = MV[o];
        uint64_t VL = wL ? MV[o - 1] : 0ULL;
        uint64_t VR = wR ? MV[o + 1] : 0ULL;
        uint64_t C = VM;

        // prefetch the a=1 row pair (rows rc-1, rc+1; words w-1,w,w+1)
        uint64_t fM0 = MV[o - 8],            fM1 = MV[o + 8];
        uint64_t fL0 = wL ? MV[o - 9] : 0ULL, fL1 = wL ? MV[o + 7] : 0ULL;
        uint64_t fR0 = wR ? MV[o - 7] : 0ULL, fR1 = wR ? MV[o + 9] : 0ULL;

        #pragma unroll
        for (int a = 1; a <= 9; ++a) {
            uint64_t NM = fM0 | fM1;
            uint64_t NL = fL0 | fL1;
            uint64_t NR = fR0 | fR1;
            if (a < 9) {                       // prefetch iteration a+1
                int lo = o - 8 * (a + 1), hi = o + 8 * (a + 1);
                fM0 = MV[lo];                  fM1 = MV[hi];
                fL0 = wL ? MV[lo - 1] : 0ULL;  fL1 = wL ? MV[hi - 1] : 0ULL;
                fR0 = wR ? MV[lo + 1] : 0ULL;  fR1 = wR ? MV[hi + 1] : 0ULL;
            }
            uint64_t SL = NL, SM = NM, SR = NR;
            const int m = a - 1;
            if (m >= 1) {
                SM |= (SM << 1) | (SM >> 1) | (SL >> 63) | (SR << 63);
                SL |= SL << 1; SR |= SR >> 1;
            }
            if (m >= 2) {
                const int s = (m == 2) ? 1 : 2;
                SM |= (SM << s) | (SM >> s) | (SL >> (64 - s)) | (SR << (64 - s));
                SL |= SL << s; SR |= SR >> s;
            }
            if (m >= 4) {
                const int s = (m - 3 < 4) ? (m - 3) : 4;
                SM |= (SM << s) | (SM >> s) | (SL >> (64 - s)) | (SR << (64 - s));
                SL |= SL << s; SR |= SR >> s;
            }
            if (m >= 8) {
                const int s = m - 7;
                SM |= (SM << s) | (SM >> s) | (SL >> (64 - s)) | (SR << (64 - s));
                SL |= SL << s; SR |= SR >> s;
            }
            C |= SM;
            VL |= NL; VM |= NM; VR |= NR;
            C |= (VM << a) | (VM >> a) | (VL >> (64 - a)) | (VR << (64 - a));
            dsum += __popcll(T & ~C);
        }
    }

    // ---- Packed reductions: 2 floats + 5 u32 (16-bit fields; wave sums
    // bounded: counters <= 64*32, dsum <= 64*640 < 2^16) -> 7 butterflies.
    unsigned r0, r1, r2, r3, r4;
    if (isStencil) {
        unsigned c3  = (unsigned)( cpack        & 0x7F);
        unsigned c4  = (unsigned)((cpack >> 7 ) & 0x7F);
        unsigned c5  = (unsigned)((cpack >> 14) & 0x7F);
        unsigned c6  = (unsigned)((cpack >> 21) & 0x7F);
        unsigned c7  = (unsigned)((cpack >> 28) & 0x7F);
        unsigned c8  = (unsigned)((cpack >> 35) & 0x7F);
        unsigned c9  = (unsigned)((cpack >> 42) & 0x7F);
        unsigned c10 = (unsigned)((cpack >> 49) & 0x7F);
        unsigned c11 = (unsigned)((cpack >> 56) & 0x7F);
        r0 = c3 | (c4 << 16); r1 = c5 | (c6 << 16); r2 = c7 | (c8 << 16);
        r3 = c9 | (c10 << 16); r4 = c11;
    } else {
        r0 = (unsigned)dsum | ((unsigned)dcnt << 16);
        r1 = 0; r2 = 0; r3 = 0; r4 = 0;
    }
    #pragma unroll
    for (int off = 32; off; off >>= 1) {
        v0 += __shfl_down(v0, off, 64);
        v1 += __shfl_down(v1, off, 64);
        r0 += __shfl_down(r0, off, 64);
        r1 += __shfl_down(r1, off, 64);
        r2 += __shfl_down(r2, off, 64);
        r3 += __shfl_down(r3, off, 64);
        r4 += __shfl_down(r4, off, 64);
    }
    if (lane == 0) {
        redf[wid][0] = v0; redf[wid][1] = v1;
        redu[wid][0] = r0; redu[wid][1] = r1; redu[wid][2] = r2;
        redu[wid][3] = r3; redu[wid][4] = r4;
    }
    __syncthreads();
    if (tid < 16) {
        int k = tid;
        float s = 0.f;
        if (k < 2) {
            #pragma unroll
            for (int wv = 0; wv < NW; ++wv) s += redf[wv][k];
        } else if (k == 2) {               // sum(g) = dcnt_g (waves 4-7 high)
            unsigned u = 0;
            for (int wv = 4; wv < 8; ++wv) u += redu[wv][0] >> 16;
            s = (float)u;
        } else if (k <= 10) {              // counters from stencil waves 8-15
            int pair = (k - 3) >> 1, hi = (k - 3) & 1;
            unsigned u = 0;
            for (int wv = 8; wv < 16; ++wv) u += (redu[wv][pair] >> (hi * 16)) & 0xFFFFu;
            s = (float)u;
        } else if (k == 11) {
            unsigned u = 0;
            for (int wv = 8; wv < 16; ++wv) u += redu[wv][4];
            s = (float)u;
        } else {                           // 12..15: dsum/dcnt p (0-3) g (4-7)
            int base = (k < 14) ? 0 : 4, hi = k & 1;
            unsigned u = 0;
            for (int wv = base; wv < base + 4; ++wv)
                u += (redu[wv][0] >> (hi * 16)) & 0xFFFFu;
            s = (float)u;
        }
        part[fid * NACC + k] = s;
    }
}

// ---------------------------------------------------------------------------
// Final: reduce 512x16 partials -> 32x16 -> scalar. One block, deterministic.
// ---------------------------------------------------------------------------
__global__ __launch_bounds__(512) void final_kernel(
    const float* __restrict__ part, float* __restrict__ out)
{
    __shared__ float sacc[BATCH][NACC];
    __shared__ float tri[BATCH][3];
    int t = threadIdx.x;
    {
        int b = t >> 4, k = t & 15;
        float s = 0.f;
        #pragma unroll 4
        for (int j = 0; j < NTILE; ++j)            // fid = j*32 + b
            s += part[((j << 5) + b) * NACC + k];
        sacc[b][k] = s;
    }
    __syncthreads();
    if (t < BATCH) {
        const float* a = sacc[t];
        float inter = a[0], psum = a[1], gsum = a[2];
        float dice = (2.f * inter + 1.f) / (psum + gsum + 1.f);

        float pe = a[3], pm = a[4], pj = a[5];
        float ge = a[6], gm = a[7], gj = a[8];
        float ie = a[9], im = a[10], ij = a[11];
        float e_iou = (ie + 1.f) / (pe + ge - ie + 1.f);
        float m_iou = (im + 1.f) / (pm + gm - im + 1.f);
        float j_iou = (ij + 1.f) / (pj + gj - ij + 1.f);
        float total = ge + gj + gm + 1.f;
        float sloss = 1.f - ((ge / total) * e_iou + (gj / total) * j_iou + (gm / total) * m_iou);

        float p2g = a[12] / (a[13] + 1.f);
        float g2p = a[14] / (a[15] + 1.f);
        float med = ((p2g + g2p) * 0.5f) / 10.f;
        tri[t][0] = dice; tri[t][1] = sloss; tri[t][2] = med;
    }
    __syncthreads();
    if (t == 0) {
        float dice = 0.f, sloss = 0.f, med = 0.f;
        for (int b = 0; b < BATCH; ++b) {
            dice += tri[b][0]; sloss += tri[b][1]; med += tri[b][2];
        }
        float dice_loss  = 1.f - dice / (float)BATCH;
        float structural = sloss / (float)BATCH;
        float medial     = med / (float)BATCH;
        float avg = (dice_loss + structural + medial) / 3.f;
        float r = dice_loss  / (dice_loss  + 1.f) * avg
                + structural / (structural + 1.f) * avg
                + medial     / (medial     + 1.f) * avg;
        out[0] = r;
    }
}

extern "C" void kernel_launch(void* const* d_in, const int* in_sizes, int n_in,
                              void* d_out, int out_size, void* d_ws, size_t ws_size,
                              hipStream_t stream)
{
    const float* pred = (const float*)d_in[0];
    const float* gt   = (const float*)d_in[1];
    float* part = (float*)d_ws;
    float* out  = (float*)d_out;

    fused_kernel<<<dim3(NBLK), NT, 0, stream>>>(pred, gt, part);
    final_kernel<<<1, 512, 0, stream>>>(part, out);
}

// Round 2
// 129.616 us; speedup vs baseline: 1.3918x; 1.3918x over previous
//
#include <hip/hip_runtime.h>
#include <stdint.h>

#define BATCH 32
#define H 512
#define W 512
#define NACC 16
#define TH 32              // center rows per tile
#define HALO 9             // coverage steps a=1..9
#define RH (TH + 2*HALO)   // 50 rows incl. halo
#define NWORDS (RH*8)      // 400 mask words per image
#define NT 1024
#define NW (NT/64)         // 16 waves
#define NTILE (H/TH)       // 16
#define NBLK (NTILE*BATCH) // 512 blocks = 2/CU

// part[fid*NACC + k] per-block partials (no atomics in the SUMS, deterministic):
//  0: sum(p*g)  1: sum(p)  2: sum(g)
//  3: cnt_pe 4: cnt_pm 5: cnt_pj  6: cnt_ge 7: cnt_gm 8: cnt_gj
//  9: int_e 10: int_m 11: int_j
// 12: dsum_p2g 13: cnt_p2g 14: dsum_g2p 15: cnt_g2p
//
// R1 lesson: backend targets 8 waves/EU (64-VGPR cap) despite LB(NT,4) min.
// R0 body sits at 44 VGPR; any added pipelining must stay under ~60 or it
// spills to scratch (R1: 89 MB scratch writes, 2x regression). Fused body
// below is the verified R0 version verbatim; only the final reduction is
// merged in via last-block ticket (saves the 2nd launch + drain gap).

__global__ __launch_bounds__(NT, 4) void fused_kernel(
    const float* __restrict__ pred, const float* __restrict__ gt,
    float* __restrict__ part, unsigned* __restrict__ ticket,
    float* __restrict__ out)
{
    __shared__ uint64_t MpS[NWORDS + 2];   // single-buffer + pad word each end
    __shared__ uint64_t MgS[NWORDS + 2];
    __shared__ float    EC[2][TH];         // pred colsums at cols 255|256
    __shared__ float    redf[NW][2];
    __shared__ unsigned redu[NW][5];
    __shared__ unsigned done;
    __shared__ float    sacc[BATCH][NACC]; // elected-block final reduce
    __shared__ float    tri[BATCH][3];

    uint64_t* Mp = MpS + 1;   // flat index o = row*8 + word
    uint64_t* Mg = MgS + 1;

    // fid = tile*32 + b: vertically-adjacent tiles of one image are 32 apart
    // => same XCD under mod-8 round-robin dispatch (halo rows share L2).
    int fid  = blockIdx.x;
    int b    = fid & 31;
    int tile = fid >> 5;

    const float* pimg = pred + (size_t)b * H * W;
    const float* gimg = gt   + (size_t)b * H * W;
    int y0 = tile * TH;
    int tid = threadIdx.x, lane = tid & 63, wid = tid >> 6;

    // ---- Phase 1: ballot masks + dice sums, rows y0-9..y0+40.
    // 400 word-tasks, x4 unroll: 8 global loads in flight per wave iteration.
    float v0 = 0.f, v1 = 0.f;
    for (int s0 = wid; s0 < NWORDS; s0 += 4 * NW) {
        float vp[4], vg[4];
        #pragma unroll
        for (int u = 0; u < 4; ++u) {
            int s = s0 + u * NW;
            vp[u] = 0.f; vg[u] = 0.f;
            int ry = y0 - HALO + (s >> 3);
            if (s < NWORDS && (unsigned)ry < (unsigned)H) {
                int i0 = ry * W + (s & 7) * 64 + lane;
                vp[u] = pimg[i0]; vg[u] = gimg[i0];
            }
        }
        #pragma unroll
        for (int u = 0; u < 4; ++u) {
            int s = s0 + u * NW;
            if (s < NWORDS) {                 // wave-uniform
                unsigned long long mp = __ballot(vp[u] > 0.5f);
                unsigned long long mg = __ballot(vg[u] > 0.5f);
                if (lane == 0) { Mp[s] = mp; Mg[s] = mg; }
                int r = s >> 3;
                if (r >= HALO && r < HALO + TH) {
                    v1 += vp[u];
                    v0 += (vg[u] > 0.5f) ? vp[u] : 0.f;
                }
            }
        }
    }
    if (tid == 0) { MpS[0] = 0; MpS[NWORDS + 1] = 0; MgS[0] = 0; MgS[NWORDS + 1] = 0; }

    // Stencil-wave pre-barrier prefetch (latency overlaps the barrier drain)
    bool isStencil = tid >= 512;
    int idx = tid & 511;
    int qi = idx & 127, h2 = idx >> 7;    // h2 in 0..3, 8 rows each
    int x4 = qi * 4;
    int ys = y0 + h2 * 8;
    float4 pm4 = make_float4(0, 0, 0, 0), pc4 = make_float4(0, 0, 0, 0);
    if (isStencil) {
        if (ys > 0) pm4 = *(const float4*)(pimg + (size_t)(ys - 1) * W + x4);
        pc4 = *(const float4*)(pimg + (size_t)ys * W + x4);
    }

    // pred edge colsums (cols 255,256) for the cross-wave stencil halo
    if (tid < 2 * TH) {
        int c = tid >> 5, r = tid & (TH - 1);
        int y = y0 + r, col = 255 + c;
        float sum = (y > 0     ? pimg[(size_t)(y - 1) * W + col] : 0.f)
                  +              pimg[(size_t)y * W + col]
                  + (y < H - 1 ? pimg[(size_t)(y + 1) * W + col] : 0.f);
        EC[c][r] = sum;
    }
    __syncthreads();
    // ======== NO MORE BARRIERS until the final reduce ========

    uint64_t cpack = 0ULL;      // stencil waves: 9 counters, 7-bit fields
    int dsum = 0, dcnt = 0;     // distance waves

    if (isStencil) {
        // ---- Stencil: pred via floats (rolling rows), gt via bit popcounts
        int wdx = qi >> 4;                    // gt word for this quad
        int ss = (qi & 15) * 4;               // bit offset of x4 in word
        auto win6 = [&](int rb) -> uint32_t {
            const uint64_t* row = &Mg[rb * 8];
            uint64_t bm = row[wdx];
            if (ss == 0) {
                uint64_t lo = wdx ? row[wdx - 1] : 0ULL;
                return (uint32_t)(((bm << 1) | (lo >> 63)) & 0x3FULL);
            }
            uint32_t v = (uint32_t)((bm >> (ss - 1)) & 0x3FULL);
            if (ss == 60) {
                uint64_t hi = (wdx < 7) ? row[wdx + 1] : 0ULL;
                v |= ((uint32_t)hi & 1u) << 5;
            }
            return v;
        };
        int rb0 = h2 * 8 + HALO - 1;          // bit-row of (ys-1)
        uint32_t wU = win6(rb0), wM = win6(rb0 + 1);

        for (int r = 0; r < 8; ++r) {
            int y = ys + r;
            float4 pp4 = (y < H - 1) ? *(const float4*)(pimg + (size_t)(y + 1) * W + x4)
                                     : make_float4(0, 0, 0, 0);
            uint32_t wD = win6(rb0 + 2 + r);
            int ry = h2 * 8 + r;

            float ps[6];
            ps[1] = pm4.x + pc4.x + pp4.x; ps[2] = pm4.y + pc4.y + pp4.y;
            ps[3] = pm4.z + pc4.z + pp4.z; ps[4] = pm4.w + pc4.w + pp4.w;
            float psl = __shfl_up(ps[4], 1, 64);
            float psr = __shfl_down(ps[1], 1, 64);
            if (lane == 0)  psl = (qi == 0)   ? 0.f : EC[0][ry];
            if (lane == 63) psr = (qi == 127) ? 0.f : EC[1][ry];
            ps[0] = psl; ps[5] = psr;

            float pcv[4] = {pc4.x, pc4.y, pc4.z, pc4.w};
            #pragma unroll
            for (int j = 0; j < 4; ++j) {
                float np = ps[j] + ps[j + 1] + ps[j + 2] - pcv[j];
                bool pon = pcv[j] > 0.5f;
                bool pe  = pon && (np == 1.f);
                bool pmb = pon && (np == 2.f);
                bool pjb = pon && (np > 2.f);
                uint32_t n9 = ((wU >> j) & 7u) | (((wM >> j) & 7u) << 3) | (((wD >> j) & 7u) << 6);
                uint32_t cen = (wM >> (j + 1)) & 1u;
                int ng = __popc(n9) - (int)cen;
                bool gon = cen != 0u;
                bool ge  = gon && (ng == 1);
                bool gmb = gon && (ng == 2);
                bool gjb = gon && (ng > 2);
                cpack += (uint64_t)pe
                       | ((uint64_t)pmb << 7)
                       | ((uint64_t)pjb << 14)
                       | ((uint64_t)ge  << 21)
                       | ((uint64_t)gmb << 28)
                       | ((uint64_t)gjb << 35)
                       | ((uint64_t)(pe  && ge)  << 42)
                       | ((uint64_t)(pmb && gmb) << 49)
                       | ((uint64_t)(pjb && gjb) << 56);
            }
            pm4 = pc4; pc4 = pp4; wU = wM; wM = wD;
        }
    } else {
        // ---- Distance: barrier-free register dilation (verified R10-R12).
        // C_a = S_a(V_a); incremental C_a = C_{a-1}|S_{a-1}(N_a)|shift_a(V_a)
        bool isP = tid < 256;                  // waves 0-3: p2g; 4-7: g2p
        int di = tid & 255;
        int o  = (HALO + (di >> 3)) * 8 + (di & 7);  // rc in [9,40]
        int w  = di & 7;
        bool wL = (w > 0), wR = (w < 7);
        const uint64_t* MT = isP ? Mp : Mg;
        const uint64_t* MV = isP ? Mg : Mp;

        uint64_t T = MT[o];
        dcnt = __popcll(T);
        dsum = dcnt;                           // a=0 baseline (dist >= 1)
        uint64_t VM = MV[o];
        uint64_t VL = wL ? MV[o - 1] : 0ULL;
        uint64_t VR = wR ? MV[o + 1] : 0ULL;
        uint64_t C = VM;

        #pragma unroll
        for (int a = 1; a <= 9; ++a) {
            int lo = o - 8 * a, hi = o + 8 * a;
            uint64_t NM = MV[lo] | MV[hi];
            uint64_t NL = wL ? (MV[lo - 1] | MV[hi - 1]) : 0ULL;
            uint64_t NR = wR ? (MV[lo + 1] | MV[hi + 1]) : 0ULL;
            uint64_t SL = NL, SM = NM, SR = NR;
            const int m = a - 1;
            if (m >= 1) {
                SM |= (SM << 1) | (SM >> 1) | (SL >> 63) | (SR << 63);
                SL |= SL << 1; SR |= SR >> 1;
            }
            if (m >= 2) {
                const int s = (m == 2) ? 1 : 2;
                SM |= (SM << s) | (SM >> s) | (SL >> (64 - s)) | (SR << (64 - s));
                SL |= SL << s; SR |= SR >> s;
            }
            if (m >= 4) {
                const int s = (m - 3 < 4) ? (m - 3) : 4;
                SM |= (SM << s) | (SM >> s) | (SL >> (64 - s)) | (SR << (64 - s));
                SL |= SL << s; SR |= SR >> s;
            }
            if (m >= 8) {
                const int s = m - 7;
                SM |= (SM << s) | (SM >> s) | (SL >> (64 - s)) | (SR << (64 - s));
                SL |= SL << s; SR |= SR >> s;
            }
            C |= SM;
            VL |= NL; VM |= NM; VR |= NR;
            C |= (VM << a) | (VM >> a) | (VL >> (64 - a)) | (VR << (64 - a));
            dsum += __popcll(T & ~C);
        }
    }

    // ---- Packed reductions: 2 floats + 5 u32 (16-bit fields; wave sums
    // bounded: counters <= 64*32, dsum <= 64*640 < 2^16) -> 7 butterflies.
    unsigned r0, r1, r2, r3, r4;
    if (isStencil) {
        unsigned c3  = (unsigned)( cpack        & 0x7F);
        unsigned c4  = (unsigned)((cpack >> 7 ) & 0x7F);
        unsigned c5  = (unsigned)((cpack >> 14) & 0x7F);
        unsigned c6  = (unsigned)((cpack >> 21) & 0x7F);
        unsigned c7  = (unsigned)((cpack >> 28) & 0x7F);
        unsigned c8  = (unsigned)((cpack >> 35) & 0x7F);
        unsigned c9  = (unsigned)((cpack >> 42) & 0x7F);
        unsigned c10 = (unsigned)((cpack >> 49) & 0x7F);
        unsigned c11 = (unsigned)((cpack >> 56) & 0x7F);
        r0 = c3 | (c4 << 16); r1 = c5 | (c6 << 16); r2 = c7 | (c8 << 16);
        r3 = c9 | (c10 << 16); r4 = c11;
    } else {
        r0 = (unsigned)dsum | ((unsigned)dcnt << 16);
        r1 = 0; r2 = 0; r3 = 0; r4 = 0;
    }
    #pragma unroll
    for (int off = 32; off; off >>= 1) {
        v0 += __shfl_down(v0, off, 64);
        v1 += __shfl_down(v1, off, 64);
        r0 += __shfl_down(r0, off, 64);
        r1 += __shfl_down(r1, off, 64);
        r2 += __shfl_down(r2, off, 64);
        r3 += __shfl_down(r3, off, 64);
        r4 += __shfl_down(r4, off, 64);
    }
    if (lane == 0) {
        redf[wid][0] = v0; redf[wid][1] = v1;
        redu[wid][0] = r0; redu[wid][1] = r1; redu[wid][2] = r2;
        redu[wid][3] = r3; redu[wid][4] = r4;
    }
    __syncthreads();
    if (tid < 16) {
        int k = tid;
        float s = 0.f;
        if (k < 2) {
            #pragma unroll
            for (int wv = 0; wv < NW; ++wv) s += redf[wv][k];
        } else if (k == 2) {               // sum(g) = dcnt_g (waves 4-7 high)
            unsigned u = 0;
            for (int wv = 4; wv < 8; ++wv) u += redu[wv][0] >> 16;
            s = (float)u;
        } else if (k <= 10) {              // counters from stencil waves 8-15
            int pair = (k - 3) >> 1, hi = (k - 3) & 1;
            unsigned u = 0;
            for (int wv = 8; wv < 16; ++wv) u += (redu[wv][pair] >> (hi * 16)) & 0xFFFFu;
            s = (float)u;
        } else if (k == 11) {
            unsigned u = 0;
            for (int wv = 8; wv < 16; ++wv) u += redu[wv][4];
            s = (float)u;
        } else {                           // 12..15: dsum/dcnt p (0-3) g (4-7)
            int base = (k < 14) ? 0 : 4, hi = k & 1;
            unsigned u = 0;
            for (int wv = base; wv < base + 4; ++wv)
                u += (redu[wv][0] >> (hi * 16)) & 0xFFFFu;
            s = (float)u;
        }
        part[fid * NACC + k] = s;
    }

    // ---- Last-block-finishes final reduce (replaces 2nd launch + drain).
    // atomic only ELECTS a block; sums are read in fixed order with the same
    // arithmetic as the old final_kernel -> bit-identical result.
    __syncthreads();                       // part[] stores drained (vmcnt 0)
    if (tid == 0) {
        __threadfence();                   // release part[] to device scope
        done = atomicAdd(ticket, 1u);
    }
    __syncthreads();
    if (done == NBLK - 1) {
        __threadfence();                   // acquire other blocks' part[]
        int t = tid;
        if (t < 512) {
            int bb = t >> 4, k = t & 15;
            float s = 0.f;
            #pragma unroll 4
            for (int j = 0; j < NTILE; ++j)            // fid = j*32 + bb
                s += part[((j << 5) + bb) * NACC + k];
            sacc[bb][k] = s;
        }
        __syncthreads();
        if (t < BATCH) {
            const float* a = sacc[t];
            float inter = a[0], psum = a[1], gsum = a[2];
            float dice = (2.f * inter + 1.f) / (psum + gsum + 1.f);

            float pe = a[3], pm = a[4], pj = a[5];
            float ge = a[6], gm = a[7], gj = a[8];
            float ie = a[9], im = a[10], ij = a[11];
            float e_iou = (ie + 1.f) / (pe + ge - ie + 1.f);
            float m_iou = (im + 1.f) / (pm + gm - im + 1.f);
            float j_iou = (ij + 1.f) / (pj + gj - ij + 1.f);
            float total = ge + gj + gm + 1.f;
            float sloss = 1.f - ((ge / total) * e_iou + (gj / total) * j_iou + (gm / total) * m_iou);

            float p2g = a[12] / (a[13] + 1.f);
            float g2p = a[14] / (a[15] + 1.f);
            float med = ((p2g + g2p) * 0.5f) / 10.f;
            tri[t][0] = dice; tri[t][1] = sloss; tri[t][2] = med;
        }
        __syncthreads();
        if (t == 0) {
            float dice = 0.f, sloss = 0.f, med = 0.f;
            for (int bb = 0; bb < BATCH; ++bb) {
                dice += tri[bb][0]; sloss += tri[bb][1]; med += tri[bb][2];
            }
            float dice_loss  = 1.f - dice / (float)BATCH;
            float structural = sloss / (float)BATCH;
            float medial     = med / (float)BATCH;
            float avg = (dice_loss + structural + medial) / 3.f;
            float r = dice_loss  / (dice_loss  + 1.f) * avg
                    + structural / (structural + 1.f) * avg
                    + medial     / (medial     + 1.f) * avg;
            out[0] = r;
        }
    }
}

extern "C" void kernel_launch(void* const* d_in, const int* in_sizes, int n_in,
                              void* d_out, int out_size, void* d_ws, size_t ws_size,
                              hipStream_t stream)
{
    const float* pred = (const float*)d_in[0];
    const float* gt   = (const float*)d_in[1];
    float* part = (float*)d_ws;
    unsigned* ticket = (unsigned*)((char*)d_ws + NBLK * NACC * sizeof(float));
    float* out  = (float*)d_out;

    hipMemsetAsync(ticket, 0, sizeof(unsigned), stream);
    fused_kernel<<<dim3(NBLK), NT, 0, stream>>>(pred, gt, part, ticket, out);
}

// Round 3
// 118.376 us; speedup vs baseline: 1.5240x; 1.0949x over previous
//
#include <hip/hip_runtime.h>
#include <stdint.h>

#define BATCH 32
#define H 512
#define W 512
#define NACC 16
#define TH 32              // center rows per tile
#define HALO 9             // coverage steps a=1..9
#define RH (TH + 2*HALO)   // 50 rows incl. halo
#define NWORDS (RH*8)      // 400 mask words per image
#define NT 1024
#define NW (NT/64)         // 16 waves
#define NTILE (H/TH)       // 16
#define NBLK (NTILE*BATCH) // 512 blocks = 2/CU
#define PROWS 34           // pred float rows in LDS: y0-1 .. y0+32 (win r 8..41)

// part[fid*NACC + k] per-block partials (no atomics, deterministic):
//  0: sum(p*g)  1: sum(p)  2: sum(g)
//  3: cnt_pe 4: cnt_pm 5: cnt_pj  6: cnt_ge 7: cnt_gm 8: cnt_gj
//  9: int_e 10: int_m 11: int_j
// 12: dsum_p2g 13: cnt_p2g 14: dsum_g2p 15: cnt_g2p
//
// R1 lesson: backend targets 8 waves/EU (64-VGPR cap) despite LB(NT,4) min.
// R0 body is 44 VGPR; added state must stay under ~60 or scratch spills
// (R1: 89 MB scratch writes, 2x regression).
// R2 lesson: 2nd launch costs ~nothing (graph back-to-back); the last-block
// ticket merge COST ~10us (per-block device fence = L2 writeback + serial
// tail). Two-kernel structure restored.
// R3: phase 1 tees pred floats (rows y0-1..y0+32) into LDS; stencil phase
// reads LDS (unguarded ds_read_b128) instead of guarded global float4 ->
// removes the dominant exposed global latency. OOB rows are zero in LDS
// (guarded loads give vp=0, store is unconditional), so stencil needs no
// edge branches. LDS/block 76.8KB -> still 2 blocks/CU.

__global__ __launch_bounds__(NT, 4) void fused_kernel(
    const float* __restrict__ pred, const float* __restrict__ gt,
    float* __restrict__ part)
{
    __shared__ uint64_t MpS[NWORDS + 2];   // single-buffer + pad word each end
    __shared__ uint64_t MgS[NWORDS + 2];
    __shared__ float    Pf[PROWS * W];     // pred float plane (68KB)
    __shared__ float    EC[2][TH];         // pred colsums at cols 255|256
    __shared__ float    redf[NW][2];
    __shared__ unsigned redu[NW][5];

    uint64_t* Mp = MpS + 1;   // flat index o = row*8 + word
    uint64_t* Mg = MgS + 1;

    // fid = tile*32 + b: vertically-adjacent tiles of one image are 32 apart
    // => same XCD under mod-8 round-robin dispatch (halo rows share L2).
    int fid  = blockIdx.x;
    int b    = fid & 31;
    int tile = fid >> 5;

    const float* pimg = pred + (size_t)b * H * W;
    const float* gimg = gt   + (size_t)b * H * W;
    int y0 = tile * TH;
    int tid = threadIdx.x, lane = tid & 63, wid = tid >> 6;

    // ---- Phase 1: ballot masks + dice sums + pred->LDS tee, rows y0-9..y0+40.
    // 400 word-tasks, x4 unroll: 8 global loads in flight per wave iteration.
    float v0 = 0.f, v1 = 0.f;
    for (int s0 = wid; s0 < NWORDS; s0 += 4 * NW) {
        float vp[4], vg[4];
        #pragma unroll
        for (int u = 0; u < 4; ++u) {
            int s = s0 + u * NW;
            vp[u] = 0.f; vg[u] = 0.f;
            int ry = y0 - HALO + (s >> 3);
            if (s < NWORDS && (unsigned)ry < (unsigned)H) {
                int i0 = ry * W + (s & 7) * 64 + lane;
                vp[u] = pimg[i0]; vg[u] = gimg[i0];
            }
        }
        #pragma unroll
        for (int u = 0; u < 4; ++u) {
            int s = s0 + u * NW;
            if (s < NWORDS) {                 // wave-uniform
                unsigned long long mp = __ballot(vp[u] > 0.5f);
                unsigned long long mg = __ballot(vg[u] > 0.5f);
                if (lane == 0) { Mp[s] = mp; Mg[s] = mg; }
                int r = s >> 3;
                if (r >= 8 && r < 8 + PROWS)  // tee pred floats (zeros if OOB)
                    Pf[(r - 8) * W + (s & 7) * 64 + lane] = vp[u];
                if (r >= HALO && r < HALO + TH) {
                    v1 += vp[u];
                    v0 += (vg[u] > 0.5f) ? vp[u] : 0.f;
                }
            }
        }
    }
    if (tid == 0) { MpS[0] = 0; MpS[NWORDS + 1] = 0; MgS[0] = 0; MgS[NWORDS + 1] = 0; }

    bool isStencil = tid >= 512;
    int idx = tid & 511;
    int qi = idx & 127, h2 = idx >> 7;    // h2 in 0..3, 8 rows each
    int x4 = qi * 4;

    // pred edge colsums (cols 255,256) for the cross-wave stencil halo
    if (tid < 2 * TH) {
        int c = tid >> 5, r = tid & (TH - 1);
        int y = y0 + r, col = 255 + c;
        float sum = (y > 0     ? pimg[(size_t)(y - 1) * W + col] : 0.f)
                  +              pimg[(size_t)y * W + col]
                  + (y < H - 1 ? pimg[(size_t)(y + 1) * W + col] : 0.f);
        EC[c][r] = sum;
    }
    __syncthreads();
    // ======== NO MORE BARRIERS until the final reduce ========

    uint64_t cpack = 0ULL;      // stencil waves: 9 counters, 7-bit fields
    int dsum = 0, dcnt = 0;     // distance waves

    if (isStencil) {
        // ---- Stencil: pred via LDS float plane (unguarded ds_read_b128,
        // OOB rows are zeros), gt via bit popcounts from ballot masks.
        int wdx = qi >> 4;                    // gt word for this quad
        int ss = (qi & 15) * 4;               // bit offset of x4 in word
        auto win6 = [&](int rb) -> uint32_t {
            const uint64_t* row = &Mg[rb * 8];
            uint64_t bm = row[wdx];
            if (ss == 0) {
                uint64_t lo = wdx ? row[wdx - 1] : 0ULL;
                return (uint32_t)(((bm << 1) | (lo >> 63)) & 0x3FULL);
            }
            uint32_t v = (uint32_t)((bm >> (ss - 1)) & 0x3FULL);
            if (ss == 60) {
                uint64_t hi = (wdx < 7) ? row[wdx + 1] : 0ULL;
                v |= ((uint32_t)hi & 1u) << 5;
            }
            return v;
        };
        int rb0 = h2 * 8 + HALO - 1;          // bit-row of (ys-1)
        uint32_t wU = win6(rb0), wM = win6(rb0 + 1);

        int rw0 = h2 * 8;                     // Pf row of (ys-1)
        float4 pm4 = *(const float4*)(Pf + (size_t)rw0 * W + x4);
        float4 pc4 = *(const float4*)(Pf + (size_t)(rw0 + 1) * W + x4);

        for (int r = 0; r < 8; ++r) {
            float4 pp4 = *(const float4*)(Pf + (size_t)(rw0 + 2 + r) * W + x4);
            uint32_t wD = win6(rb0 + 2 + r);
            int ry = h2 * 8 + r;

            float ps[6];
            ps[1] = pm4.x + pc4.x + pp4.x; ps[2] = pm4.y + pc4.y + pp4.y;
            ps[3] = pm4.z + pc4.z + pp4.z; ps[4] = pm4.w + pc4.w + pp4.w;
            float psl = __shfl_up(ps[4], 1, 64);
            float psr = __shfl_down(ps[1], 1, 64);
            if (lane == 0)  psl = (qi == 0)   ? 0.f : EC[0][ry];
            if (lane == 63) psr = (qi == 127) ? 0.f : EC[1][ry];
            ps[0] = psl; ps[5] = psr;

            float pcv[4] = {pc4.x, pc4.y, pc4.z, pc4.w};
            #pragma unroll
            for (int j = 0; j < 4; ++j) {
                float np = ps[j] + ps[j + 1] + ps[j + 2] - pcv[j];
                bool pon = pcv[j] > 0.5f;
                bool pe  = pon && (np == 1.f);
                bool pmb = pon && (np == 2.f);
                bool pjb = pon && (np > 2.f);
                uint32_t n9 = ((wU >> j) & 7u) | (((wM >> j) & 7u) << 3) | (((wD >> j) & 7u) << 6);
                uint32_t cen = (wM >> (j + 1)) & 1u;
                int ng = __popc(n9) - (int)cen;
                bool gon = cen != 0u;
                bool ge  = gon && (ng == 1);
                bool gmb = gon && (ng == 2);
                bool gjb = gon && (ng > 2);
                cpack += (uint64_t)pe
                       | ((uint64_t)pmb << 7)
                       | ((uint64_t)pjb << 14)
                       | ((uint64_t)ge  << 21)
                       | ((uint64_t)gmb << 28)
                       | ((uint64_t)gjb << 35)
                       | ((uint64_t)(pe  && ge)  << 42)
                       | ((uint64_t)(pmb && gmb) << 49)
                       | ((uint64_t)(pjb && gjb) << 56);
            }
            pm4 = pc4; pc4 = pp4; wU = wM; wM = wD;
        }
    } else {
        // ---- Distance: barrier-free register dilation (verified R10-R12).
        // C_a = S_a(V_a); incremental C_a = C_{a-1}|S_{a-1}(N_a)|shift_a(V_a)
        bool isP = tid < 256;                  // waves 0-3: p2g; 4-7: g2p
        int di = tid & 255;
        int o  = (HALO + (di >> 3)) * 8 + (di & 7);  // rc in [9,40]
        int w  = di & 7;
        bool wL = (w > 0), wR = (w < 7);
        const uint64_t* MT = isP ? Mp : Mg;
        const uint64_t* MV = isP ? Mg : Mp;

        uint64_t T = MT[o];
        dcnt = __popcll(T);
        dsum = dcnt;                           // a=0 baseline (dist >= 1)
        uint64_t VM = MV[o];
        uint64_t VL = wL ? MV[o - 1] : 0ULL;
        uint64_t VR = wR ? MV[o + 1] : 0ULL;
        uint64_t C = VM;

        #pragma unroll
        for (int a = 1; a <= 9; ++a) {
            int lo = o - 8 * a, hi = o + 8 * a;
            uint64_t NM = MV[lo] | MV[hi];
            uint64_t NL = wL ? (MV[lo - 1] | MV[hi - 1]) : 0ULL;
            uint64_t NR = wR ? (MV[lo + 1] | MV[hi + 1]) : 0ULL;
            uint64_t SL = NL, SM = NM, SR = NR;
            const int m = a - 1;
            if (m >= 1) {
                SM |= (SM << 1) | (SM >> 1) | (SL >> 63) | (SR << 63);
                SL |= SL << 1; SR |= SR >> 1;
            }
            if (m >= 2) {
                const int s = (m == 2) ? 1 : 2;
                SM |= (SM << s) | (SM >> s) | (SL >> (64 - s)) | (SR << (64 - s));
                SL |= SL << s; SR |= SR >> s;
            }
            if (m >= 4) {
                const int s = (m - 3 < 4) ? (m - 3) : 4;
                SM |= (SM << s) | (SM >> s) | (SL >> (64 - s)) | (SR << (64 - s));
                SL |= SL << s; SR |= SR >> s;
            }
            if (m >= 8) {
                const int s = m - 7;
                SM |= (SM << s) | (SM >> s) | (SL >> (64 - s)) | (SR << (64 - s));
                SL |= SL << s; SR |= SR >> s;
            }
            C |= SM;
            VL |= NL; VM |= NM; VR |= NR;
            C |= (VM << a) | (VM >> a) | (VL >> (64 - a)) | (VR << (64 - a));
            dsum += __popcll(T & ~C);
        }
    }

    // ---- Packed reductions: 2 floats + 5 u32 (16-bit fields; wave sums
    // bounded: counters <= 64*32, dsum <= 64*640 < 2^16) -> 7 butterflies.
    unsigned r0, r1, r2, r3, r4;
    if (isStencil) {
        unsigned c3  = (unsigned)( cpack        & 0x7F);
        unsigned c4  = (unsigned)((cpack >> 7 ) & 0x7F);
        unsigned c5  = (unsigned)((cpack >> 14) & 0x7F);
        unsigned c6  = (unsigned)((cpack >> 21) & 0x7F);
        unsigned c7  = (unsigned)((cpack >> 28) & 0x7F);
        unsigned c8  = (unsigned)((cpack >> 35) & 0x7F);
        unsigned c9  = (unsigned)((cpack >> 42) & 0x7F);
        unsigned c10 = (unsigned)((cpack >> 49) & 0x7F);
        unsigned c11 = (unsigned)((cpack >> 56) & 0x7F);
        r0 = c3 | (c4 << 16); r1 = c5 | (c6 << 16); r2 = c7 | (c8 << 16);
        r3 = c9 | (c10 << 16); r4 = c11;
    } else {
        r0 = (unsigned)dsum | ((unsigned)dcnt << 16);
        r1 = 0; r2 = 0; r3 = 0; r4 = 0;
    }
    #pragma unroll
    for (int off = 32; off; off >>= 1) {
        v0 += __shfl_down(v0, off, 64);
        v1 += __shfl_down(v1, off, 64);
        r0 += __shfl_down(r0, off, 64);
        r1 += __shfl_down(r1, off, 64);
        r2 += __shfl_down(r2, off, 64);
        r3 += __shfl_down(r3, off, 64);
        r4 += __shfl_down(r4, off, 64);
    }
    if (lane == 0) {
        redf[wid][0] = v0; redf[wid][1] = v1;
        redu[wid][0] = r0; redu[wid][1] = r1; redu[wid][2] = r2;
        redu[wid][3] = r3; redu[wid][4] = r4;
    }
    __syncthreads();
    if (tid < 16) {
        int k = tid;
        float s = 0.f;
        if (k < 2) {
            #pragma unroll
            for (int wv = 0; wv < NW; ++wv) s += redf[wv][k];
        } else if (k == 2) {               // sum(g) = dcnt_g (waves 4-7 high)
            unsigned u = 0;
            for (int wv = 4; wv < 8; ++wv) u += redu[wv][0] >> 16;
            s = (float)u;
        } else if (k <= 10) {              // counters from stencil waves 8-15
            int pair = (k - 3) >> 1, hi = (k - 3) & 1;
            unsigned u = 0;
            for (int wv = 8; wv < 16; ++wv) u += (redu[wv][pair] >> (hi * 16)) & 0xFFFFu;
            s = (float)u;
        } else if (k == 11) {
            unsigned u = 0;
            for (int wv = 8; wv < 16; ++wv) u += redu[wv][4];
            s = (float)u;
        } else {                           // 12..15: dsum/dcnt p (0-3) g (4-7)
            int base = (k < 14) ? 0 : 4, hi = k & 1;
            unsigned u = 0;
            for (int wv = base; wv < base + 4; ++wv)
                u += (redu[wv][0] >> (hi * 16)) & 0xFFFFu;
            s = (float)u;
        }
        part[fid * NACC + k] = s;
    }
}

// ---------------------------------------------------------------------------
// Final: reduce 512x16 partials -> 32x16 -> scalar. One block, deterministic.
// ---------------------------------------------------------------------------
__global__ __launch_bounds__(512) void final_kernel(
    const float* __restrict__ part, float* __restrict__ out)
{
    __shared__ float sacc[BATCH][NACC];
    __shared__ float tri[BATCH][3];
    int t = threadIdx.x;
    {
        int b = t >> 4, k = t & 15;
        float s = 0.f;
        #pragma unroll 4
        for (int j = 0; j < NTILE; ++j)            // fid = j*32 + b
            s += part[((j << 5) + b) * NACC + k];
        sacc[b][k] = s;
    }
    __syncthreads();
    if (t < BATCH) {
        const float* a = sacc[t];
        float inter = a[0], psum = a[1], gsum = a[2];
        float dice = (2.f * inter + 1.f) / (psum + gsum + 1.f);

        float pe = a[3], pm = a[4], pj = a[5];
        float ge = a[6], gm = a[7], gj = a[8];
        float ie = a[9], im = a[10], ij = a[11];
        float e_iou = (ie + 1.f) / (pe + ge - ie + 1.f);
        float m_iou = (im + 1.f) / (pm + gm - im + 1.f);
        float j_iou = (ij + 1.f) / (pj + gj - ij + 1.f);
        float total = ge + gj + gm + 1.f;
        float sloss = 1.f - ((ge / total) * e_iou + (gj / total) * j_iou + (gm / total) * m_iou);

        float p2g = a[12] / (a[13] + 1.f);
        float g2p = a[14] / (a[15] + 1.f);
        float med = ((p2g + g2p) * 0.5f) / 10.f;
        tri[t][0] = dice; tri[t][1] = sloss; tri[t][2] = med;
    }
    __syncthreads();
    if (t == 0) {
        float dice = 0.f, sloss = 0.f, med = 0.f;
        for (int b = 0; b < BATCH; ++b) {
            dice += tri[b][0]; sloss += tri[b][1]; med += tri[b][2];
        }
        float dice_loss  = 1.f - dice / (float)BATCH;
        float structural = sloss / (float)BATCH;
        float medial     = med / (float)BATCH;
        float avg = (dice_loss + structural + medial) / 3.f;
        float r = dice_loss  / (dice_loss  + 1.f) * avg
                + structural / (structural + 1.f) * avg
                + medial     / (medial     + 1.f) * avg;
        out[0] = r;
    }
}

extern "C" void kernel_launch(void* const* d_in, const int* in_sizes, int n_in,
                              void* d_out, int out_size, void* d_ws, size_t ws_size,
                              hipStream_t stream)
{
    const float* pred = (const float*)d_in[0];
    const float* gt   = (const float*)d_in[1];
    float* part = (float*)d_ws;
    float* out  = (float*)d_out;

    fused_kernel<<<dim3(NBLK), NT, 0, stream>>>(pred, gt, part);
    final_kernel<<<1, 512, 0, stream>>>(part, out);
}

// Round 4
// 116.205 us; speedup vs baseline: 1.5525x; 1.0187x over previous
//
#include <hip/hip_runtime.h>
#include <stdint.h>

#define BATCH 32
#define H 512
#define W 512
#define NACC 16
#define TH 32              // center rows per tile
#define HALO 9             // coverage steps a=1..9
#define RH (TH + 2*HALO)   // 50 rows incl. halo
#define NWORDS (RH*8)      // 400 mask words per image
#define NT 1024
#define NW (NT/64)         // 16 waves
#define NTILE (H/TH)       // 16
#define NBLK (NTILE*BATCH) // 512 blocks = 2/CU
#define PROWS 34           // pred float rows in LDS: y0-1 .. y0+32 (win r 8..41)

// part[fid*NACC + k] per-block partials (no atomics, deterministic):
//  0: sum(p*g)  1: sum(p)  2: sum(g)
//  3: cnt_pe 4: cnt_pm 5: cnt_pj  6: cnt_ge 7: cnt_gm 8: cnt_gj
//  9: int_e 10: int_m 11: int_j
// 12: dsum_p2g 13: cnt_p2g 14: dsum_g2p 15: cnt_g2p
//
// R1 lesson: backend targets 8 waves/EU (64-VGPR cap) despite LB(NT,4) min.
// R0 body is 44 VGPR; added state must stay under ~60 or scratch spills
// (R1: 89 MB scratch writes, 2x regression).
// R2 lesson: 2nd launch costs ~nothing (graph back-to-back); the last-block
// ticket merge COST ~10us (per-block device fence + serial tail).
// R3 lesson: stencil global float4 reads were already latency-hidden (LDS
// tee was neutral; kept since it removes guarded loads). Kernel is ~55%
// stalled with ~20us of pure VALU issue -> attack stalls, not traffic.
// R4: wave-uniform early exit in the distance dilation. dsum accumulates
// popc(T & ~C) and C is monotone non-decreasing, so once T&~C==0 wave-wide
// every later iteration adds exactly 0 -> break is bit-exact for ANY input.
// Random-data densities (gt 10%, pred-on 50%) make p2g exit at a~5 and
// g2p at a~2-3 (vs fixed 9): ~60% of distance work + LDS latency removed,
// rebalancing the post-barrier phases.

__global__ __launch_bounds__(NT, 4) void fused_kernel(
    const float* __restrict__ pred, const float* __restrict__ gt,
    float* __restrict__ part)
{
    __shared__ uint64_t MpS[NWORDS + 2];   // single-buffer + pad word each end
    __shared__ uint64_t MgS[NWORDS + 2];
    __shared__ float    Pf[PROWS * W];     // pred float plane (68KB)
    __shared__ float    EC[2][TH];         // pred colsums at cols 255|256
    __shared__ float    redf[NW][2];
    __shared__ unsigned redu[NW][5];

    uint64_t* Mp = MpS + 1;   // flat index o = row*8 + word
    uint64_t* Mg = MgS + 1;

    // fid = tile*32 + b: vertically-adjacent tiles of one image are 32 apart
    // => same XCD under mod-8 round-robin dispatch (halo rows share L2).
    int fid  = blockIdx.x;
    int b    = fid & 31;
    int tile = fid >> 5;

    const float* pimg = pred + (size_t)b * H * W;
    const float* gimg = gt   + (size_t)b * H * W;
    int y0 = tile * TH;
    int tid = threadIdx.x, lane = tid & 63, wid = tid >> 6;

    // ---- Phase 1: ballot masks + dice sums + pred->LDS tee, rows y0-9..y0+40.
    // 400 word-tasks, x4 unroll: 8 global loads in flight per wave iteration.
    float v0 = 0.f, v1 = 0.f;
    for (int s0 = wid; s0 < NWORDS; s0 += 4 * NW) {
        float vp[4], vg[4];
        #pragma unroll
        for (int u = 0; u < 4; ++u) {
            int s = s0 + u * NW;
            vp[u] = 0.f; vg[u] = 0.f;
            int ry = y0 - HALO + (s >> 3);
            if (s < NWORDS && (unsigned)ry < (unsigned)H) {
                int i0 = ry * W + (s & 7) * 64 + lane;
                vp[u] = pimg[i0]; vg[u] = gimg[i0];
            }
        }
        #pragma unroll
        for (int u = 0; u < 4; ++u) {
            int s = s0 + u * NW;
            if (s < NWORDS) {                 // wave-uniform
                unsigned long long mp = __ballot(vp[u] > 0.5f);
                unsigned long long mg = __ballot(vg[u] > 0.5f);
                if (lane == 0) { Mp[s] = mp; Mg[s] = mg; }
                int r = s >> 3;
                if (r >= 8 && r < 8 + PROWS)  // tee pred floats (zeros if OOB)
                    Pf[(r - 8) * W + (s & 7) * 64 + lane] = vp[u];
                if (r >= HALO && r < HALO + TH) {
                    v1 += vp[u];
                    v0 += (vg[u] > 0.5f) ? vp[u] : 0.f;
                }
            }
        }
    }
    if (tid == 0) { MpS[0] = 0; MpS[NWORDS + 1] = 0; MgS[0] = 0; MgS[NWORDS + 1] = 0; }

    bool isStencil = tid >= 512;
    int idx = tid & 511;
    int qi = idx & 127, h2 = idx >> 7;    // h2 in 0..3, 8 rows each
    int x4 = qi * 4;

    // pred edge colsums (cols 255,256) for the cross-wave stencil halo
    if (tid < 2 * TH) {
        int c = tid >> 5, r = tid & (TH - 1);
        int y = y0 + r, col = 255 + c;
        float sum = (y > 0     ? pimg[(size_t)(y - 1) * W + col] : 0.f)
                  +              pimg[(size_t)y * W + col]
                  + (y < H - 1 ? pimg[(size_t)(y + 1) * W + col] : 0.f);
        EC[c][r] = sum;
    }
    __syncthreads();
    // ======== NO MORE BARRIERS until the final reduce ========

    uint64_t cpack = 0ULL;      // stencil waves: 9 counters, 7-bit fields
    int dsum = 0, dcnt = 0;     // distance waves

    if (isStencil) {
        // ---- Stencil: pred via LDS float plane (unguarded ds_read_b128,
        // OOB rows are zeros), gt via bit popcounts from ballot masks.
        int wdx = qi >> 4;                    // gt word for this quad
        int ss = (qi & 15) * 4;               // bit offset of x4 in word
        auto win6 = [&](int rb) -> uint32_t {
            const uint64_t* row = &Mg[rb * 8];
            uint64_t bm = row[wdx];
            if (ss == 0) {
                uint64_t lo = wdx ? row[wdx - 1] : 0ULL;
                return (uint32_t)(((bm << 1) | (lo >> 63)) & 0x3FULL);
            }
            uint32_t v = (uint32_t)((bm >> (ss - 1)) & 0x3FULL);
            if (ss == 60) {
                uint64_t hi = (wdx < 7) ? row[wdx + 1] : 0ULL;
                v |= ((uint32_t)hi & 1u) << 5;
            }
            return v;
        };
        int rb0 = h2 * 8 + HALO - 1;          // bit-row of (ys-1)
        uint32_t wU = win6(rb0), wM = win6(rb0 + 1);

        int rw0 = h2 * 8;                     // Pf row of (ys-1)
        float4 pm4 = *(const float4*)(Pf + (size_t)rw0 * W + x4);
        float4 pc4 = *(const float4*)(Pf + (size_t)(rw0 + 1) * W + x4);

        for (int r = 0; r < 8; ++r) {
            float4 pp4 = *(const float4*)(Pf + (size_t)(rw0 + 2 + r) * W + x4);
            uint32_t wD = win6(rb0 + 2 + r);
            int ry = h2 * 8 + r;

            float ps[6];
            ps[1] = pm4.x + pc4.x + pp4.x; ps[2] = pm4.y + pc4.y + pp4.y;
            ps[3] = pm4.z + pc4.z + pp4.z; ps[4] = pm4.w + pc4.w + pp4.w;
            float psl = __shfl_up(ps[4], 1, 64);
            float psr = __shfl_down(ps[1], 1, 64);
            if (lane == 0)  psl = (qi == 0)   ? 0.f : EC[0][ry];
            if (lane == 63) psr = (qi == 127) ? 0.f : EC[1][ry];
            ps[0] = psl; ps[5] = psr;

            float pcv[4] = {pc4.x, pc4.y, pc4.z, pc4.w};
            #pragma unroll
            for (int j = 0; j < 4; ++j) {
                float np = ps[j] + ps[j + 1] + ps[j + 2] - pcv[j];
                bool pon = pcv[j] > 0.5f;
                bool pe  = pon && (np == 1.f);
                bool pmb = pon && (np == 2.f);
                bool pjb = pon && (np > 2.f);
                uint32_t n9 = ((wU >> j) & 7u) | (((wM >> j) & 7u) << 3) | (((wD >> j) & 7u) << 6);
                uint32_t cen = (wM >> (j + 1)) & 1u;
                int ng = __popc(n9) - (int)cen;
                bool gon = cen != 0u;
                bool ge  = gon && (ng == 1);
                bool gmb = gon && (ng == 2);
                bool gjb = gon && (ng > 2);
                cpack += (uint64_t)pe
                       | ((uint64_t)pmb << 7)
                       | ((uint64_t)pjb << 14)
                       | ((uint64_t)ge  << 21)
                       | ((uint64_t)gmb << 28)
                       | ((uint64_t)gjb << 35)
                       | ((uint64_t)(pe  && ge)  << 42)
                       | ((uint64_t)(pmb && gmb) << 49)
                       | ((uint64_t)(pjb && gjb) << 56);
            }
            pm4 = pc4; pc4 = pp4; wU = wM; wM = wD;
        }
    } else {
        // ---- Distance: barrier-free register dilation (verified R10-R12).
        // C_a = S_a(V_a); incremental C_a = C_{a-1}|S_{a-1}(N_a)|shift_a(V_a)
        bool isP = tid < 256;                  // waves 0-3: p2g; 4-7: g2p
        int di = tid & 255;
        int o  = (HALO + (di >> 3)) * 8 + (di & 7);  // rc in [9,40]
        int w  = di & 7;
        bool wL = (w > 0), wR = (w < 7);
        const uint64_t* MT = isP ? Mp : Mg;
        const uint64_t* MV = isP ? Mg : Mp;

        uint64_t T = MT[o];
        dcnt = __popcll(T);
        dsum = dcnt;                           // a=0 baseline (dist >= 1)
        uint64_t VM = MV[o];
        uint64_t VL = wL ? MV[o - 1] : 0ULL;
        uint64_t VR = wR ? MV[o + 1] : 0ULL;
        uint64_t C = VM;

        #pragma unroll
        for (int a = 1; a <= 9; ++a) {
            int lo = o - 8 * a, hi = o + 8 * a;
            uint64_t NM = MV[lo] | MV[hi];
            uint64_t NL = wL ? (MV[lo - 1] | MV[hi - 1]) : 0ULL;
            uint64_t NR = wR ? (MV[lo + 1] | MV[hi + 1]) : 0ULL;
            uint64_t SL = NL, SM = NM, SR = NR;
            const int m = a - 1;
            if (m >= 1) {
                SM |= (SM << 1) | (SM >> 1) | (SL >> 63) | (SR << 63);
                SL |= SL << 1; SR |= SR >> 1;
            }
            if (m >= 2) {
                const int s = (m == 2) ? 1 : 2;
                SM |= (SM << s) | (SM >> s) | (SL >> (64 - s)) | (SR << (64 - s));
                SL |= SL << s; SR |= SR >> s;
            }
            if (m >= 4) {
                const int s = (m - 3 < 4) ? (m - 3) : 4;
                SM |= (SM << s) | (SM >> s) | (SL >> (64 - s)) | (SR << (64 - s));
                SL |= SL << s; SR |= SR >> s;
            }
            if (m >= 8) {
                const int s = m - 7;
                SM |= (SM << s) | (SM >> s) | (SL >> (64 - s)) | (SR << (64 - s));
                SL |= SL << s; SR |= SR >> s;
            }
            C |= SM;
            VL |= NL; VM |= NM; VR |= NR;
            C |= (VM << a) | (VM >> a) | (VL >> (64 - a)) | (VR << (64 - a));
            uint64_t rem = T & ~C;
            dsum += __popcll(rem);
            // C is monotone non-decreasing => once rem==0 wave-wide, every
            // remaining iteration adds exactly 0 to dsum. Bit-exact exit.
            if (__all(rem == 0ULL)) break;
        }
    }

    // ---- Packed reductions: 2 floats + 5 u32 (16-bit fields; wave sums
    // bounded: counters <= 64*32, dsum <= 64*640 < 2^16) -> 7 butterflies.
    unsigned r0, r1, r2, r3, r4;
    if (isStencil) {
        unsigned c3  = (unsigned)( cpack        & 0x7F);
        unsigned c4  = (unsigned)((cpack >> 7 ) & 0x7F);
        unsigned c5  = (unsigned)((cpack >> 14) & 0x7F);
        unsigned c6  = (unsigned)((cpack >> 21) & 0x7F);
        unsigned c7  = (unsigned)((cpack >> 28) & 0x7F);
        unsigned c8  = (unsigned)((cpack >> 35) & 0x7F);
        unsigned c9  = (unsigned)((cpack >> 42) & 0x7F);
        unsigned c10 = (unsigned)((cpack >> 49) & 0x7F);
        unsigned c11 = (unsigned)((cpack >> 56) & 0x7F);
        r0 = c3 | (c4 << 16); r1 = c5 | (c6 << 16); r2 = c7 | (c8 << 16);
        r3 = c9 | (c10 << 16); r4 = c11;
    } else {
        r0 = (unsigned)dsum | ((unsigned)dcnt << 16);
        r1 = 0; r2 = 0; r3 = 0; r4 = 0;
    }
    #pragma unroll
    for (int off = 32; off; off >>= 1) {
        v0 += __shfl_down(v0, off, 64);
        v1 += __shfl_down(v1, off, 64);
        r0 += __shfl_down(r0, off, 64);
        r1 += __shfl_down(r1, off, 64);
        r2 += __shfl_down(r2, off, 64);
        r3 += __shfl_down(r3, off, 64);
        r4 += __shfl_down(r4, off, 64);
    }
    if (lane == 0) {
        redf[wid][0] = v0; redf[wid][1] = v1;
        redu[wid][0] = r0; redu[wid][1] = r1; redu[wid][2] = r2;
        redu[wid][3] = r3; redu[wid][4] = r4;
    }
    __syncthreads();
    if (tid < 16) {
        int k = tid;
        float s = 0.f;
        if (k < 2) {
            #pragma unroll
            for (int wv = 0; wv < NW; ++wv) s += redf[wv][k];
        } else if (k == 2) {               // sum(g) = dcnt_g (waves 4-7 high)
            unsigned u = 0;
            for (int wv = 4; wv < 8; ++wv) u += redu[wv][0] >> 16;
            s = (float)u;
        } else if (k <= 10) {              // counters from stencil waves 8-15
            int pair = (k - 3) >> 1, hi = (k - 3) & 1;
            unsigned u = 0;
            for (int wv = 8; wv < 16; ++wv) u += (redu[wv][pair] >> (hi * 16)) & 0xFFFFu;
            s = (float)u;
        } else if (k == 11) {
            unsigned u = 0;
            for (int wv = 8; wv < 16; ++wv) u += redu[wv][4];
            s = (float)u;
        } else {                           // 12..15: dsum/dcnt p (0-3) g (4-7)
            int base = (k < 14) ? 0 : 4, hi = k & 1;
            unsigned u = 0;
            for (int wv = base; wv < base + 4; ++wv)
                u += (redu[wv][0] >> (hi * 16)) & 0xFFFFu;
            s = (float)u;
        }
        part[fid * NACC + k] = s;
    }
}

// ---------------------------------------------------------------------------
// Final: reduce 512x16 partials -> 32x16 -> scalar. One block, deterministic.
// ---------------------------------------------------------------------------
__global__ __launch_bounds__(512) void final_kernel(
    const float* __restrict__ part, float* __restrict__ out)
{
    __shared__ float sacc[BATCH][NACC];
    __shared__ float tri[BATCH][3];
    int t = threadIdx.x;
    {
        int b = t >> 4, k = t & 15;
        float s = 0.f;
        #pragma unroll 4
        for (int j = 0; j < NTILE; ++j)            // fid = j*32 + b
            s += part[((j << 5) + b) * NACC + k];
        sacc[b][k] = s;
    }
    __syncthreads();
    if (t < BATCH) {
        const float* a = sacc[t];
        float inter = a[0], psum = a[1], gsum = a[2];
        float dice = (2.f * inter + 1.f) / (psum + gsum + 1.f);

        float pe = a[3], pm = a[4], pj = a[5];
        float ge = a[6], gm = a[7], gj = a[8];
        float ie = a[9], im = a[10], ij = a[11];
        float e_iou = (ie + 1.f) / (pe + ge - ie + 1.f);
        float m_iou = (im + 1.f) / (pm + gm - im + 1.f);
        float j_iou = (ij + 1.f) / (pj + gj - ij + 1.f);
        float total = ge + gj + gm + 1.f;
        float sloss = 1.f - ((ge / total) * e_iou + (gj / total) * j_iou + (gm / total) * m_iou);

        float p2g = a[12] / (a[13] + 1.f);
        float g2p = a[14] / (a[15] + 1.f);
        float med = ((p2g + g2p) * 0.5f) / 10.f;
        tri[t][0] = dice; tri[t][1] = sloss; tri[t][2] = med;
    }
    __syncthreads();
    if (t == 0) {
        float dice = 0.f, sloss = 0.f, med = 0.f;
        for (int b = 0; b < BATCH; ++b) {
            dice += tri[b][0]; sloss += tri[b][1]; med += tri[b][2];
        }
        float dice_loss  = 1.f - dice / (float)BATCH;
        float structural = sloss / (float)BATCH;
        float medial     = med / (float)BATCH;
        float avg = (dice_loss + structural + medial) / 3.f;
        float r = dice_loss  / (dice_loss  + 1.f) * avg
                + structural / (structural + 1.f) * avg
                + medial     / (medial     + 1.f) * avg;
        out[0] = r;
    }
}

extern "C" void kernel_launch(void* const* d_in, const int* in_sizes, int n_in,
                              void* d_out, int out_size, void* d_ws, size_t ws_size,
                              hipStream_t stream)
{
    const float* pred = (const float*)d_in[0];
    const float* gt   = (const float*)d_in[1];
    float* part = (float*)d_ws;
    float* out  = (float*)d_out;

    fused_kernel<<<dim3(NBLK), NT, 0, stream>>>(pred, gt, part);
    final_kernel<<<1, 512, 0, stream>>>(part, out);
}

// Round 5
// 111.990 us; speedup vs baseline: 1.6109x; 1.0376x over previous
//
#include <hip/hip_runtime.h>
#include <stdint.h>

#define BATCH 32
#define H 512
#define W 512
#define NACC 16
#define TH 32              // center rows per tile
#define HALO 9             // coverage steps a=1..9
#define RH (TH + 2*HALO)   // 50 rows incl. halo
#define NWORDS (RH*8)      // 400 mask words per image
#define NT 1024
#define NW (NT/64)         // 16 waves
#define NTILE (H/TH)       // 16
#define NBLK (NTILE*BATCH) // 512 blocks = 2/CU

// part[fid*NACC + k] per-block partials (no atomics, deterministic):
//  0: sum(p*g)  1: sum(p)  2: sum(g)
//  3: cnt_pe 4: cnt_pm 5: cnt_pj  6: cnt_ge 7: cnt_gm 8: cnt_gj
//  9: int_e 10: int_m 11: int_j
// 12: dsum_p2g 13: cnt_p2g 14: dsum_g2p 15: cnt_g2p
//
// R1: backend targets 8 waves/EU (64-VGPR cap); stay well under 64 or spill
//     storm (89 MB scratch writes, 2x regression).
// R2: 2nd launch costs ~nothing; last-block ticket merge COST ~10us.
// R3: stencil global float4 reads already latency-hidden (Pf tee neutral).
// R4: occupancy doubled (38->67%) with flat duration -> NOT latency-bound;
//     throughput-bound on issued VALU work (~19us issue of 44us). Stencil's
//     per-pixel gt classification (~40 VALU/px) is the biggest chunk.
// R5: bit-sliced gt classification. 256 distance-wave threads build
//     Ge/Gm/Gj class masks (64 px/word) via a carry-save-adder tree over
//     the 8 shifted neighbor masks (~26 u64 ops/word vs ~15/px), publish
//     via a 2nd barrier, and produce cnt_ge/gm/gj via popcll. Stencil then
//     does 3 bit-extracts/px (win6/n9/popc/classify deleted; cpack 9->6
//     fields). Pf plane dropped (R3-neutral) -> LDS 76.8KB -> ~13KB.

__global__ __launch_bounds__(NT, 4) void fused_kernel(
    const float* __restrict__ pred, const float* __restrict__ gt,
    float* __restrict__ part)
{
    __shared__ uint64_t MpS[NWORDS + 2];   // single-buffer + pad word each end
    __shared__ uint64_t MgS[NWORDS + 2];
    __shared__ uint64_t Ge[TH * 8];        // gt class masks, center rows
    __shared__ uint64_t Gm[TH * 8];
    __shared__ uint64_t Gj[TH * 8];
    __shared__ float    EC[2][TH];         // pred colsums at cols 255|256
    __shared__ float    redf[NW][2];
    __shared__ unsigned redu[NW][3];

    uint64_t* Mp = MpS + 1;   // flat index o = row*8 + word
    uint64_t* Mg = MgS + 1;

    // fid = tile*32 + b: vertically-adjacent tiles of one image are 32 apart
    // => same XCD under mod-8 round-robin dispatch (halo rows share L2).
    int fid  = blockIdx.x;
    int b    = fid & 31;
    int tile = fid >> 5;

    const float* pimg = pred + (size_t)b * H * W;
    const float* gimg = gt   + (size_t)b * H * W;
    int y0 = tile * TH;
    int tid = threadIdx.x, lane = tid & 63, wid = tid >> 6;

    // ---- Phase 1: ballot masks + dice sums, rows y0-9..y0+40.
    // 400 word-tasks, x4 unroll: 8 global loads in flight per wave iteration.
    float v0 = 0.f, v1 = 0.f;
    for (int s0 = wid; s0 < NWORDS; s0 += 4 * NW) {
        float vp[4], vg[4];
        #pragma unroll
        for (int u = 0; u < 4; ++u) {
            int s = s0 + u * NW;
            vp[u] = 0.f; vg[u] = 0.f;
            int ry = y0 - HALO + (s >> 3);
            if (s < NWORDS && (unsigned)ry < (unsigned)H) {
                int i0 = ry * W + (s & 7) * 64 + lane;
                vp[u] = pimg[i0]; vg[u] = gimg[i0];
            }
        }
        #pragma unroll
        for (int u = 0; u < 4; ++u) {
            int s = s0 + u * NW;
            if (s < NWORDS) {                 // wave-uniform
                unsigned long long mp = __ballot(vp[u] > 0.5f);
                unsigned long long mg = __ballot(vg[u] > 0.5f);
                if (lane == 0) { Mp[s] = mp; Mg[s] = mg; }
                int r = s >> 3;
                if (r >= HALO && r < HALO + TH) {
                    v1 += vp[u];
                    v0 += (vg[u] > 0.5f) ? vp[u] : 0.f;
                }
            }
        }
    }
    if (tid == 0) { MpS[0] = 0; MpS[NWORDS + 1] = 0; MgS[0] = 0; MgS[NWORDS + 1] = 0; }

    // Stencil-wave pre-barrier prefetch (latency overlaps the barrier drain)
    bool isStencil = tid >= 512;
    int idx = tid & 511;
    int qi = idx & 127, h2 = idx >> 7;    // h2 in 0..3, 8 rows each
    int x4 = qi * 4;
    int ys = y0 + h2 * 8;
    float4 pm4 = make_float4(0, 0, 0, 0), pc4 = make_float4(0, 0, 0, 0);
    if (isStencil) {
        if (ys > 0) pm4 = *(const float4*)(pimg + (size_t)(ys - 1) * W + x4);
        pc4 = *(const float4*)(pimg + (size_t)ys * W + x4);
    }

    // pred edge colsums (cols 255,256) for the cross-wave stencil halo
    if (tid < 2 * TH) {
        int c = tid >> 5, r = tid & (TH - 1);
        int y = y0 + r, col = 255 + c;
        float sum = (y > 0     ? pimg[(size_t)(y - 1) * W + col] : 0.f)
                  +              pimg[(size_t)y * W + col]
                  + (y < H - 1 ? pimg[(size_t)(y + 1) * W + col] : 0.f);
        EC[c][r] = sum;
    }
    __syncthreads();                      // barrier 1: masks ready

    // ---- Bit-sliced gt classification (threads 0..255, one word each).
    // count of 8 neighbors per bit-position via CSA tree; exact integer
    // equivalence with the reference conv (gt binary, zero-padded edges).
    unsigned cge = 0, cgm = 0, cgj = 0;
    if (tid < 256) {
        int r = tid >> 3, w = tid & 7;
        int oM = (HALO + r) * 8 + w;
        bool wl = (w > 0), wr = (w < 7);
        uint64_t A  = Mg[oM - 8], Bm = Mg[oM], Cm = Mg[oM + 8];
        uint64_t AL = wl ? Mg[oM - 9] : 0ULL, AR = wr ? Mg[oM - 7] : 0ULL;
        uint64_t BL = wl ? Mg[oM - 1] : 0ULL, BR = wr ? Mg[oM + 1] : 0ULL;
        uint64_t CL = wl ? Mg[oM + 7] : 0ULL, CR = wr ? Mg[oM + 9] : 0ULL;
        uint64_t Aw = (A  << 1) | (AL >> 63), Ae = (A  >> 1) | (AR << 63);
        uint64_t Bw = (Bm << 1) | (BL >> 63), Be = (Bm >> 1) | (BR << 63);
        uint64_t Cw = (Cm << 1) | (CL >> 63), Ce = (Cm >> 1) | (CR << 63);
        // sum 8 one-bit addends: Aw,A,Ae,Bw,Be,Cw,Cm,Ce -> bits b0..b3
        uint64_t c1, c2, c3, c5;
        uint64_t t;
        t = Aw ^ A;  uint64_t s1 = t ^ Ae;  c1 = (Aw & A)  | (Ae & t);
        t = Bw ^ Be; uint64_t s2 = t ^ Cw;  c2 = (Bw & Be) | (Cw & t);
        t = Cm ^ Ce; uint64_t s3 = t ^ s1;  c3 = (Cm & Ce) | (s1 & t);
        uint64_t b0 = s2 ^ s3, c4 = s2 & s3;
        t = c1 ^ c2; uint64_t s5 = t ^ c3;  c5 = (c1 & c2) | (c3 & t);
        uint64_t b1 = s5 ^ c4, c6 = s5 & c4;
        uint64_t b2 = c5 ^ c6, b3 = c5 & c6;
        uint64_t nz23 = ~(b2 | b3);
        uint64_t ge = Bm & b0 & ~b1 & nz23;
        uint64_t gm = Bm & b1 & ~b0 & nz23;
        uint64_t gj = Bm & (b2 | b3 | (b1 & b0));
        Ge[tid] = ge; Gm[tid] = gm; Gj[tid] = gj;
        cge = (unsigned)__popcll(ge);
        cgm = (unsigned)__popcll(gm);
        cgj = (unsigned)__popcll(gj);
    }
    __syncthreads();                      // barrier 2: class masks ready
    // ======== NO MORE BARRIERS until the final reduce ========

    uint64_t cpack = 0ULL;      // stencil waves: 6 counters, 7-bit fields
    int dsum = 0, dcnt = 0;     // distance waves

    if (isStencil) {
        // ---- Stencil: pred via floats (global, rolling rows), gt via
        // precomputed class-mask bit tests.
        int wdx = qi >> 4;                    // gt word for this quad
        int ss = (qi & 15) * 4;               // bit offset of x4 in word

        for (int r = 0; r < 8; ++r) {
            int y = ys + r;
            float4 pp4 = (y < H - 1) ? *(const float4*)(pimg + (size_t)(y + 1) * W + x4)
                                     : make_float4(0, 0, 0, 0);
            int ry = h2 * 8 + r;
            uint64_t gew = Ge[ry * 8 + wdx];
            uint64_t gmw = Gm[ry * 8 + wdx];
            uint64_t gjw = Gj[ry * 8 + wdx];

            float ps[6];
            ps[1] = pm4.x + pc4.x + pp4.x; ps[2] = pm4.y + pc4.y + pp4.y;
            ps[3] = pm4.z + pc4.z + pp4.z; ps[4] = pm4.w + pc4.w + pp4.w;
            float psl = __shfl_up(ps[4], 1, 64);
            float psr = __shfl_down(ps[1], 1, 64);
            if (lane == 0)  psl = (qi == 0)   ? 0.f : EC[0][ry];
            if (lane == 63) psr = (qi == 127) ? 0.f : EC[1][ry];
            ps[0] = psl; ps[5] = psr;

            float pcv[4] = {pc4.x, pc4.y, pc4.z, pc4.w};
            #pragma unroll
            for (int j = 0; j < 4; ++j) {
                float np = ps[j] + ps[j + 1] + ps[j + 2] - pcv[j];
                bool pon = pcv[j] > 0.5f;
                bool pe  = pon && (np == 1.f);
                bool pmb = pon && (np == 2.f);
                bool pjb = pon && (np > 2.f);
                unsigned geb = (unsigned)(gew >> (ss + j)) & 1u;
                unsigned gmb = (unsigned)(gmw >> (ss + j)) & 1u;
                unsigned gjb = (unsigned)(gjw >> (ss + j)) & 1u;
                cpack += (uint64_t)pe
                       | ((uint64_t)pmb << 7)
                       | ((uint64_t)pjb << 14)
                       | ((uint64_t)(pe  && geb) << 21)
                       | ((uint64_t)(pmb && gmb) << 28)
                       | ((uint64_t)(pjb && gjb) << 35);
            }
            pm4 = pc4; pc4 = pp4;
        }
    } else {
        // ---- Distance: barrier-free register dilation + bit-exact early
        // exit (R4): C monotone => once T&~C==0 wave-wide, later iters add 0.
        bool isP = tid < 256;                  // waves 0-3: p2g; 4-7: g2p
        int di = tid & 255;
        int o  = (HALO + (di >> 3)) * 8 + (di & 7);  // rc in [9,40]
        int w  = di & 7;
        bool wL = (w > 0), wR = (w < 7);
        const uint64_t* MT = isP ? Mp : Mg;
        const uint64_t* MV = isP ? Mg : Mp;

        uint64_t T = MT[o];
        dcnt = __popcll(T);
        dsum = dcnt;                           // a=0 baseline (dist >= 1)
        uint64_t VM = MV[o];
        uint64_t VL = wL ? MV[o - 1] : 0ULL;
        uint64_t VR = wR ? MV[o + 1] : 0ULL;
        uint64_t C = VM;

        #pragma unroll
        for (int a = 1; a <= 9; ++a) {
            int lo = o - 8 * a, hi = o + 8 * a;
            uint64_t NM = MV[lo] | MV[hi];
            uint64_t NL = wL ? (MV[lo - 1] | MV[hi - 1]) : 0ULL;
            uint64_t NR = wR ? (MV[lo + 1] | MV[hi + 1]) : 0ULL;
            uint64_t SL = NL, SM = NM, SR = NR;
            const int m = a - 1;
            if (m >= 1) {
                SM |= (SM << 1) | (SM >> 1) | (SL >> 63) | (SR << 63);
                SL |= SL << 1; SR |= SR >> 1;
            }
            if (m >= 2) {
                const int s = (m == 2) ? 1 : 2;
                SM |= (SM << s) | (SM >> s) | (SL >> (64 - s)) | (SR << (64 - s));
                SL |= SL << s; SR |= SR >> s;
            }
            if (m >= 4) {
                const int s = (m - 3 < 4) ? (m - 3) : 4;
                SM |= (SM << s) | (SM >> s) | (SL >> (64 - s)) | (SR << (64 - s));
                SL |= SL << s; SR |= SR >> s;
            }
            if (m >= 8) {
                const int s = m - 7;
                SM |= (SM << s) | (SM >> s) | (SL >> (64 - s)) | (SR << (64 - s));
                SL |= SL << s; SR |= SR >> s;
            }
            C |= SM;
            VL |= NL; VM |= NM; VR |= NR;
            C |= (VM << a) | (VM >> a) | (VL >> (64 - a)) | (VR << (64 - a));
            uint64_t rem = T & ~C;
            dsum += __popcll(rem);
            if (__all(rem == 0ULL)) break;
        }
    }

    // ---- Packed reductions: 2 floats + 3 u32 (16-bit fields; wave sums
    // bounded: counters <= 64*64, dsum <= 64*640 < 2^16) -> 5 butterflies.
    unsigned r0, r1, r2;
    if (isStencil) {
        unsigned c_pe = (unsigned)( cpack        & 0x7F);
        unsigned c_pm = (unsigned)((cpack >> 7 ) & 0x7F);
        unsigned c_pj = (unsigned)((cpack >> 14) & 0x7F);
        unsigned c_ie = (unsigned)((cpack >> 21) & 0x7F);
        unsigned c_im = (unsigned)((cpack >> 28) & 0x7F);
        unsigned c_ij = (unsigned)((cpack >> 35) & 0x7F);
        r0 = c_pe | (c_pm << 16); r1 = c_pj | (c_ie << 16); r2 = c_im | (c_ij << 16);
    } else {
        r0 = (unsigned)dsum | ((unsigned)dcnt << 16);
        r1 = cge | (cgm << 16);
        r2 = cgj;
    }
    #pragma unroll
    for (int off = 32; off; off >>= 1) {
        v0 += __shfl_down(v0, off, 64);
        v1 += __shfl_down(v1, off, 64);
        r0 += __shfl_down(r0, off, 64);
        r1 += __shfl_down(r1, off, 64);
        r2 += __shfl_down(r2, off, 64);
    }
    if (lane == 0) {
        redf[wid][0] = v0; redf[wid][1] = v1;
        redu[wid][0] = r0; redu[wid][1] = r1; redu[wid][2] = r2;
    }
    __syncthreads();
    if (tid < 16) {
        int k = tid;
        float s = 0.f;
        if (k < 2) {
            #pragma unroll
            for (int wv = 0; wv < NW; ++wv) s += redf[wv][k];
        } else {
            // k: 2..15 -> (waveBase, waveCnt, reg, hi16)
            static const uint8_t WB[16] = {0,0, 4, 8,8,8, 0,0,0, 8,8,8, 0,0,4,4};
            static const uint8_t WC[16] = {0,0, 4, 8,8,8, 4,4,4, 8,8,8, 4,4,4,4};
            static const uint8_t RG[16] = {0,0, 0, 0,0,1, 1,1,2, 1,2,2, 0,0,0,0};
            static const uint8_t HI[16] = {0,0, 1, 0,1,0, 0,1,0, 1,0,1, 0,1,0,1};
            unsigned u = 0;
            for (int wv = WB[k]; wv < WB[k] + WC[k]; ++wv)
                u += (redu[wv][RG[k]] >> (HI[k] * 16)) & 0xFFFFu;
            s = (float)u;
        }
        part[fid * NACC + k] = s;
    }
}

// ---------------------------------------------------------------------------
// Final: reduce 512x16 partials -> 32x16 -> scalar. One block, deterministic.
// ---------------------------------------------------------------------------
__global__ __launch_bounds__(512) void final_kernel(
    const float* __restrict__ part, float* __restrict__ out)
{
    __shared__ float sacc[BATCH][NACC];
    __shared__ float tri[BATCH][3];
    int t = threadIdx.x;
    {
        int b = t >> 4, k = t & 15;
        float s = 0.f;
        #pragma unroll 4
        for (int j = 0; j < NTILE; ++j)            // fid = j*32 + b
            s += part[((j << 5) + b) * NACC + k];
        sacc[b][k] = s;
    }
    __syncthreads();
    if (t < BATCH) {
        const float* a = sacc[t];
        float inter = a[0], psum = a[1], gsum = a[2];
        float dice = (2.f * inter + 1.f) / (psum + gsum + 1.f);

        float pe = a[3], pm = a[4], pj = a[5];
        float ge = a[6], gm = a[7], gj = a[8];
        float ie = a[9], im = a[10], ij = a[11];
        float e_iou = (ie + 1.f) / (pe + ge - ie + 1.f);
        float m_iou = (im + 1.f) / (pm + gm - im + 1.f);
        float j_iou = (ij + 1.f) / (pj + gj - ij + 1.f);
        float total = ge + gj + gm + 1.f;
        float sloss = 1.f - ((ge / total) * e_iou + (gj / total) * j_iou + (gm / total) * m_iou);

        float p2g = a[12] / (a[13] + 1.f);
        float g2p = a[14] / (a[15] + 1.f);
        float med = ((p2g + g2p) * 0.5f) / 10.f;
        tri[t][0] = dice; tri[t][1] = sloss; tri[t][2] = med;
    }
    __syncthreads();
    if (t == 0) {
        float dice = 0.f, sloss = 0.f, med = 0.f;
        for (int b = 0; b < BATCH; ++b) {
            dice += tri[b][0]; sloss += tri[b][1]; med += tri[b][2];
        }
        float dice_loss  = 1.f - dice / (float)BATCH;
        float structural = sloss / (float)BATCH;
        float medial     = med / (float)BATCH;
        float avg = (dice_loss + structural + medial) / 3.f;
        float r = dice_loss  / (dice_loss  + 1.f) * avg
                + structural / (structural + 1.f) * avg
                + medial     / (medial     + 1.f) * avg;
        out[0] = r;
    }
}

extern "C" void kernel_launch(void* const* d_in, const int* in_sizes, int n_in,
                              void* d_out, int out_size, void* d_ws, size_t ws_size,
                              hipStream_t stream)
{
    const float* pred = (const float*)d_in[0];
    const float* gt   = (const float*)d_in[1];
    float* part = (float*)d_ws;
    float* out  = (float*)d_out;

    fused_kernel<<<dim3(NBLK), NT, 0, stream>>>(pred, gt, part);
    final_kernel<<<1, 512, 0, stream>>>(part, out);
}

// Round 6
// 111.983 us; speedup vs baseline: 1.6110x; 1.0001x over previous
//
#include <hip/hip_runtime.h>
#include <stdint.h>

#define BATCH 32
#define H 512
#define W 512
#define NACC 16
#define TH 32              // center rows per tile
#define HALO 9             // coverage steps a=1..9
#define RH (TH + 2*HALO)   // 50 rows incl. halo
#define NWORDS (RH*8)      // 400 mask words per image
#define NT 1024
#define NW (NT/64)         // 16 waves
#define NTILE (H/TH)       // 16
#define NBLK (NTILE*BATCH) // 512 blocks = 2/CU

// part[fid*NACC + k] per-block partials (no atomics, deterministic):
//  0: sum(p*g)  1: sum(p)  2: sum(g)
//  3: cnt_pe 4: cnt_pm 5: cnt_pj  6: cnt_ge 7: cnt_gm 8: cnt_gj
//  9: int_e 10: int_m 11: int_j
// 12: dsum_p2g 13: cnt_p2g 14: dsum_g2p 15: cnt_g2p
//
// R1: backend pins 64-VGPR cap (8 waves/EU); stacked +37 VGPR across three
//     phases -> spill storm (89 MB scratch writes). Add state in ONE phase
//     at a time, stay under ~60.
// R2: 2nd launch costs ~nothing; last-block ticket merge COST ~10us.
// R3: stencil global float4 reads already latency-hidden (Pf tee neutral).
// R4: occupancy 2x with flat duration -> not TLP-bound.
// R5: VALU cut 15-20% (bit-sliced gt classify) -> VALUBusy fell, duration
//     flat -> not VALU-issue-bound. Warm replay (FETCH~0) still 43.5us ->
//     not fetch-bound. Remaining suspect: exposed latency chains; phase 1
//     is 7 sequential {8 loads -> wait -> consume} round-trips.
// R6: phase-1 two-group A/B software pipeline (16 loads in flight, +16
//     VGPR, statically indexed). Same per-thread accumulation order ->
//     bitwise-identical partials.

__global__ __launch_bounds__(NT, 4) void fused_kernel(
    const float* __restrict__ pred, const float* __restrict__ gt,
    float* __restrict__ part)
{
    __shared__ uint64_t MpS[NWORDS + 2];   // single-buffer + pad word each end
    __shared__ uint64_t MgS[NWORDS + 2];
    __shared__ uint64_t Ge[TH * 8];        // gt class masks, center rows
    __shared__ uint64_t Gm[TH * 8];
    __shared__ uint64_t Gj[TH * 8];
    __shared__ float    EC[2][TH];         // pred colsums at cols 255|256
    __shared__ float    redf[NW][2];
    __shared__ unsigned redu[NW][3];

    uint64_t* Mp = MpS + 1;   // flat index o = row*8 + word
    uint64_t* Mg = MgS + 1;

    // fid = tile*32 + b: vertically-adjacent tiles of one image are 32 apart
    // => same XCD under mod-8 round-robin dispatch (halo rows share L2).
    int fid  = blockIdx.x;
    int b    = fid & 31;
    int tile = fid >> 5;

    const float* pimg = pred + (size_t)b * H * W;
    const float* gimg = gt   + (size_t)b * H * W;
    int y0 = tile * TH;
    int tid = threadIdx.x, lane = tid & 63, wid = tid >> 6;

    // ---- Phase 1: ballot masks + dice sums, rows y0-9..y0+40.
    // Two-group A/B pipeline: group g+1's 8 loads issued before group g is
    // consumed -> 16 loads in flight, ~1 exposed round-trip instead of 7.
    float v0 = 0.f, v1 = 0.f;
    float vpA[4], vgA[4], vpB[4], vgB[4];

    auto LOADG = [&](float (&vp)[4], float (&vg)[4], int s0) {
        #pragma unroll
        for (int u = 0; u < 4; ++u) {
            int s = s0 + u * NW;
            vp[u] = 0.f; vg[u] = 0.f;
            int ry = y0 - HALO + (s >> 3);
            if (s < NWORDS && (unsigned)ry < (unsigned)H) {
                int i0 = ry * W + (s & 7) * 64 + lane;
                vp[u] = pimg[i0]; vg[u] = gimg[i0];
            }
        }
    };
    auto CONS = [&](float (&vp)[4], float (&vg)[4], int s0) {
        #pragma unroll
        for (int u = 0; u < 4; ++u) {
            int s = s0 + u * NW;
            if (s < NWORDS) {                 // wave-uniform
                unsigned long long mp = __ballot(vp[u] > 0.5f);
                unsigned long long mg = __ballot(vg[u] > 0.5f);
                if (lane == 0) { Mp[s] = mp; Mg[s] = mg; }
                int r = s >> 3;
                if (r >= HALO && r < HALO + TH) {
                    v1 += vp[u];
                    v0 += (vg[u] > 0.5f) ? vp[u] : 0.f;
                }
            }
        }
    };

    LOADG(vpA, vgA, wid);
    LOADG(vpB, vgB, wid + 64);
    CONS (vpA, vgA, wid);
    LOADG(vpA, vgA, wid + 128);
    CONS (vpB, vgB, wid + 64);
    LOADG(vpB, vgB, wid + 192);
    CONS (vpA, vgA, wid + 128);
    LOADG(vpA, vgA, wid + 256);
    CONS (vpB, vgB, wid + 192);
    LOADG(vpB, vgB, wid + 320);
    CONS (vpA, vgA, wid + 256);
    LOADG(vpA, vgA, wid + 384);
    CONS (vpB, vgB, wid + 320);
    CONS (vpA, vgA, wid + 384);

    if (tid == 0) { MpS[0] = 0; MpS[NWORDS + 1] = 0; MgS[0] = 0; MgS[NWORDS + 1] = 0; }

    // Stencil-wave pre-barrier prefetch (latency overlaps the barrier drain)
    bool isStencil = tid >= 512;
    int idx = tid & 511;
    int qi = idx & 127, h2 = idx >> 7;    // h2 in 0..3, 8 rows each
    int x4 = qi * 4;
    int ys = y0 + h2 * 8;
    float4 pm4 = make_float4(0, 0, 0, 0), pc4 = make_float4(0, 0, 0, 0);
    if (isStencil) {
        if (ys > 0) pm4 = *(const float4*)(pimg + (size_t)(ys - 1) * W + x4);
        pc4 = *(const float4*)(pimg + (size_t)ys * W + x4);
    }

    // pred edge colsums (cols 255,256) for the cross-wave stencil halo
    if (tid < 2 * TH) {
        int c = tid >> 5, r = tid & (TH - 1);
        int y = y0 + r, col = 255 + c;
        float sum = (y > 0     ? pimg[(size_t)(y - 1) * W + col] : 0.f)
                  +              pimg[(size_t)y * W + col]
                  + (y < H - 1 ? pimg[(size_t)(y + 1) * W + col] : 0.f);
        EC[c][r] = sum;
    }
    __syncthreads();                      // barrier 1: masks ready

    // ---- Bit-sliced gt classification (threads 0..255, one word each).
    // count of 8 neighbors per bit-position via CSA tree; exact integer
    // equivalence with the reference conv (gt binary, zero-padded edges).
    unsigned cge = 0, cgm = 0, cgj = 0;
    if (tid < 256) {
        int r = tid >> 3, w = tid & 7;
        int oM = (HALO + r) * 8 + w;
        bool wl = (w > 0), wr = (w < 7);
        uint64_t A  = Mg[oM - 8], Bm = Mg[oM], Cm = Mg[oM + 8];
        uint64_t AL = wl ? Mg[oM - 9] : 0ULL, AR = wr ? Mg[oM - 7] : 0ULL;
        uint64_t BL = wl ? Mg[oM - 1] : 0ULL, BR = wr ? Mg[oM + 1] : 0ULL;
        uint64_t CL = wl ? Mg[oM + 7] : 0ULL, CR = wr ? Mg[oM + 9] : 0ULL;
        uint64_t Aw = (A  << 1) | (AL >> 63), Ae = (A  >> 1) | (AR << 63);
        uint64_t Bw = (Bm << 1) | (BL >> 63), Be = (Bm >> 1) | (BR << 63);
        uint64_t Cw = (Cm << 1) | (CL >> 63), Ce = (Cm >> 1) | (CR << 63);
        // sum 8 one-bit addends: Aw,A,Ae,Bw,Be,Cw,Cm,Ce -> bits b0..b3
        uint64_t c1, c2, c3, c5;
        uint64_t t;
        t = Aw ^ A;  uint64_t s1 = t ^ Ae;  c1 = (Aw & A)  | (Ae & t);
        t = Bw ^ Be; uint64_t s2 = t ^ Cw;  c2 = (Bw & Be) | (Cw & t);
        t = Cm ^ Ce; uint64_t s3 = t ^ s1;  c3 = (Cm & Ce) | (s1 & t);
        uint64_t b0 = s2 ^ s3, c4 = s2 & s3;
        t = c1 ^ c2; uint64_t s5 = t ^ c3;  c5 = (c1 & c2) | (c3 & t);
        uint64_t b1 = s5 ^ c4, c6 = s5 & c4;
        uint64_t b2 = c5 ^ c6, b3 = c5 & c6;
        uint64_t nz23 = ~(b2 | b3);
        uint64_t ge = Bm & b0 & ~b1 & nz23;
        uint64_t gm = Bm & b1 & ~b0 & nz23;
        uint64_t gj = Bm & (b2 | b3 | (b1 & b0));
        Ge[tid] = ge; Gm[tid] = gm; Gj[tid] = gj;
        cge = (unsigned)__popcll(ge);
        cgm = (unsigned)__popcll(gm);
        cgj = (unsigned)__popcll(gj);
    }
    __syncthreads();                      // barrier 2: class masks ready
    // ======== NO MORE BARRIERS until the final reduce ========

    uint64_t cpack = 0ULL;      // stencil waves: 6 counters, 7-bit fields
    int dsum = 0, dcnt = 0;     // distance waves

    if (isStencil) {
        // ---- Stencil: pred via floats (global, rolling rows), gt via
        // precomputed class-mask bit tests.
        int wdx = qi >> 4;                    // gt word for this quad
        int ss = (qi & 15) * 4;               // bit offset of x4 in word

        for (int r = 0; r < 8; ++r) {
            int y = ys + r;
            float4 pp4 = (y < H - 1) ? *(const float4*)(pimg + (size_t)(y + 1) * W + x4)
                                     : make_float4(0, 0, 0, 0);
            int ry = h2 * 8 + r;
            uint64_t gew = Ge[ry * 8 + wdx];
            uint64_t gmw = Gm[ry * 8 + wdx];
            uint64_t gjw = Gj[ry * 8 + wdx];

            float ps[6];
            ps[1] = pm4.x + pc4.x + pp4.x; ps[2] = pm4.y + pc4.y + pp4.y;
            ps[3] = pm4.z + pc4.z + pp4.z; ps[4] = pm4.w + pc4.w + pp4.w;
            float psl = __shfl_up(ps[4], 1, 64);
            float psr = __shfl_down(ps[1], 1, 64);
            if (lane == 0)  psl = (qi == 0)   ? 0.f : EC[0][ry];
            if (lane == 63) psr = (qi == 127) ? 0.f : EC[1][ry];
            ps[0] = psl; ps[5] = psr;

            float pcv[4] = {pc4.x, pc4.y, pc4.z, pc4.w};
            #pragma unroll
            for (int j = 0; j < 4; ++j) {
                float np = ps[j] + ps[j + 1] + ps[j + 2] - pcv[j];
                bool pon = pcv[j] > 0.5f;
                bool pe  = pon && (np == 1.f);
                bool pmb = pon && (np == 2.f);
                bool pjb = pon && (np > 2.f);
                unsigned geb = (unsigned)(gew >> (ss + j)) & 1u;
                unsigned gmb = (unsigned)(gmw >> (ss + j)) & 1u;
                unsigned gjb = (unsigned)(gjw >> (ss + j)) & 1u;
                cpack += (uint64_t)pe
                       | ((uint64_t)pmb << 7)
                       | ((uint64_t)pjb << 14)
                       | ((uint64_t)(pe  && geb) << 21)
                       | ((uint64_t)(pmb && gmb) << 28)
                       | ((uint64_t)(pjb && gjb) << 35);
            }
            pm4 = pc4; pc4 = pp4;
        }
    } else {
        // ---- Distance: barrier-free register dilation + bit-exact early
        // exit (R4): C monotone => once T&~C==0 wave-wide, later iters add 0.
        bool isP = tid < 256;                  // waves 0-3: p2g; 4-7: g2p
        int di = tid & 255;
        int o  = (HALO + (di >> 3)) * 8 + (di & 7);  // rc in [9,40]
        int w  = di & 7;
        bool wL = (w > 0), wR = (w < 7);
        const uint64_t* MT = isP ? Mp : Mg;
        const uint64_t* MV = isP ? Mg : Mp;

        uint64_t T = MT[o];
        dcnt = __popcll(T);
        dsum = dcnt;                           // a=0 baseline (dist >= 1)
        uint64_t VM = MV[o];
        uint64_t VL = wL ? MV[o - 1] : 0ULL;
        uint64_t VR = wR ? MV[o + 1] : 0ULL;
        uint64_t C = VM;

        #pragma unroll
        for (int a = 1; a <= 9; ++a) {
            int lo = o - 8 * a, hi = o + 8 * a;
            uint64_t NM = MV[lo] | MV[hi];
            uint64_t NL = wL ? (MV[lo - 1] | MV[hi - 1]) : 0ULL;
            uint64_t NR = wR ? (MV[lo + 1] | MV[hi + 1]) : 0ULL;
            uint64_t SL = NL, SM = NM, SR = NR;
            const int m = a - 1;
            if (m >= 1) {
                SM |= (SM << 1) | (SM >> 1) | (SL >> 63) | (SR << 63);
                SL |= SL << 1; SR |= SR >> 1;
            }
            if (m >= 2) {
                const int s = (m == 2) ? 1 : 2;
                SM |= (SM << s) | (SM >> s) | (SL >> (64 - s)) | (SR << (64 - s));
                SL |= SL << s; SR |= SR >> s;
            }
            if (m >= 4) {
                const int s = (m - 3 < 4) ? (m - 3) : 4;
                SM |= (SM << s) | (SM >> s) | (SL >> (64 - s)) | (SR << (64 - s));
                SL |= SL << s; SR |= SR >> s;
            }
            if (m >= 8) {
                const int s = m - 7;
                SM |= (SM << s) | (SM >> s) | (SL >> (64 - s)) | (SR << (64 - s));
                SL |= SL << s; SR |= SR >> s;
            }
            C |= SM;
            VL |= NL; VM |= NM; VR |= NR;
            C |= (VM << a) | (VM >> a) | (VL >> (64 - a)) | (VR << (64 - a));
            uint64_t rem = T & ~C;
            dsum += __popcll(rem);
            if (__all(rem == 0ULL)) break;
        }
    }

    // ---- Packed reductions: 2 floats + 3 u32 (16-bit fields; wave sums
    // bounded: counters <= 64*64, dsum <= 64*640 < 2^16) -> 5 butterflies.
    unsigned r0, r1, r2;
    if (isStencil) {
        unsigned c_pe = (unsigned)( cpack        & 0x7F);
        unsigned c_pm = (unsigned)((cpack >> 7 ) & 0x7F);
        unsigned c_pj = (unsigned)((cpack >> 14) & 0x7F);
        unsigned c_ie = (unsigned)((cpack >> 21) & 0x7F);
        unsigned c_im = (unsigned)((cpack >> 28) & 0x7F);
        unsigned c_ij = (unsigned)((cpack >> 35) & 0x7F);
        r0 = c_pe | (c_pm << 16); r1 = c_pj | (c_ie << 16); r2 = c_im | (c_ij << 16);
    } else {
        r0 = (unsigned)dsum | ((unsigned)dcnt << 16);
        r1 = cge | (cgm << 16);
        r2 = cgj;
    }
    #pragma unroll
    for (int off = 32; off; off >>= 1) {
        v0 += __shfl_down(v0, off, 64);
        v1 += __shfl_down(v1, off, 64);
        r0 += __shfl_down(r0, off, 64);
        r1 += __shfl_down(r1, off, 64);
        r2 += __shfl_down(r2, off, 64);
    }
    if (lane == 0) {
        redf[wid][0] = v0; redf[wid][1] = v1;
        redu[wid][0] = r0; redu[wid][1] = r1; redu[wid][2] = r2;
    }
    __syncthreads();
    if (tid < 16) {
        int k = tid;
        float s = 0.f;
        if (k < 2) {
            #pragma unroll
            for (int wv = 0; wv < NW; ++wv) s += redf[wv][k];
        } else {
            // k: 2..15 -> (waveBase, waveCnt, reg, hi16)
            static const uint8_t WB[16] = {0,0, 4, 8,8,8, 0,0,0, 8,8,8, 0,0,4,4};
            static const uint8_t WC[16] = {0,0, 4, 8,8,8, 4,4,4, 8,8,8, 4,4,4,4};
            static const uint8_t RG[16] = {0,0, 0, 0,0,1, 1,1,2, 1,2,2, 0,0,0,0};
            static const uint8_t HI[16] = {0,0, 1, 0,1,0, 0,1,0, 1,0,1, 0,1,0,1};
            unsigned u = 0;
            for (int wv = WB[k]; wv < WB[k] + WC[k]; ++wv)
                u += (redu[wv][RG[k]] >> (HI[k] * 16)) & 0xFFFFu;
            s = (float)u;
        }
        part[fid * NACC + k] = s;
    }
}

// ---------------------------------------------------------------------------
// Final: reduce 512x16 partials -> 32x16 -> scalar. One block, deterministic.
// ---------------------------------------------------------------------------
__global__ __launch_bounds__(512) void final_kernel(
    const float* __restrict__ part, float* __restrict__ out)
{
    __shared__ float sacc[BATCH][NACC];
    __shared__ float tri[BATCH][3];
    int t = threadIdx.x;
    {
        int b = t >> 4, k = t & 15;
        float s = 0.f;
        #pragma unroll 4
        for (int j = 0; j < NTILE; ++j)            // fid = j*32 + b
            s += part[((j << 5) + b) * NACC + k];
        sacc[b][k] = s;
    }
    __syncthreads();
    if (t < BATCH) {
        const float* a = sacc[t];
        float inter = a[0], psum = a[1], gsum = a[2];
        float dice = (2.f * inter + 1.f) / (psum + gsum + 1.f);

        float pe = a[3], pm = a[4], pj = a[5];
        float ge = a[6], gm = a[7], gj = a[8];
        float ie = a[9], im = a[10], ij = a[11];
        float e_iou = (ie + 1.f) / (pe + ge - ie + 1.f);
        float m_iou = (im + 1.f) / (pm + gm - im + 1.f);
        float j_iou = (ij + 1.f) / (pj + gj - ij + 1.f);
        float total = ge + gj + gm + 1.f;
        float sloss = 1.f - ((ge / total) * e_iou + (gj / total) * j_iou + (gm / total) * m_iou);

        float p2g = a[12] / (a[13] + 1.f);
        float g2p = a[14] / (a[15] + 1.f);
        float med = ((p2g + g2p) * 0.5f) / 10.f;
        tri[t][0] = dice; tri[t][1] = sloss; tri[t][2] = med;
    }
    __syncthreads();
    if (t == 0) {
        float dice = 0.f, sloss = 0.f, med = 0.f;
        for (int b = 0; b < BATCH; ++b) {
            dice += tri[b][0]; sloss += tri[b][1]; med += tri[b][2];
        }
        float dice_loss  = 1.f - dice / (float)BATCH;
        float structural = sloss / (float)BATCH;
        float medial     = med / (float)BATCH;
        float avg = (dice_loss + structural + medial) / 3.f;
        float r = dice_loss  / (dice_loss  + 1.f) * avg
                + structural / (structural + 1.f) * avg
                + medial     / (medial     + 1.f) * avg;
        out[0] = r;
    }
}

extern "C" void kernel_launch(void* const* d_in, const int* in_sizes, int n_in,
                              void* d_out, int out_size, void* d_ws, size_t ws_size,
                              hipStream_t stream)
{
    const float* pred = (const float*)d_in[0];
    const float* gt   = (const float*)d_in[1];
    float* part = (float*)d_ws;
    float* out  = (float*)d_out;

    fused_kernel<<<dim3(NBLK), NT, 0, stream>>>(pred, gt, part);
    final_kernel<<<1, 512, 0, stream>>>(part, out);
}